// Round 1
// baseline (804.746 us; speedup 1.0000x reference)
//
#include <hip/hip_runtime.h>
#include <stdint.h>

// ---------------------------------------------------------------------------
// Binarized QAT CNN forward, fused per-image.
//   conv1 (f32) -> per-tensor int8 fake-quant -> sign  => ternary a1 [16,26,26]
//   conv2(a1, sign(w2)) -> sign                        => ternary h2 [16,24,24]
//   conv3(h2, sign(w3)) -> sign                        => ternary h3 [32,22,22]
//   avgpool2x2 -> [32,11,11] -> flatten(3872) @ sign(w_fc)^T + b_fc -> [10]
// Everything after conv1 is exact integer math (sums of +-1 bounded by 144 /
// 3872 are exact in f32 in the reference), so only conv1 + the global max
// (scale) are floating-point-sensitive. conv1 uses a fixed fmaf order shared
// between the max pass and the forward pass.
// ---------------------------------------------------------------------------

__device__ __forceinline__ int dot4(int a, int b, int c) {
#if __has_builtin(__builtin_amdgcn_sdot4)
  return __builtin_amdgcn_sdot4(a, b, c, false);
#else
  int r = c;
  r += (int)(int8_t)(a)       * (int)(int8_t)(b);
  r += (int)(int8_t)(a >> 8)  * (int)(int8_t)(b >> 8);
  r += (int)(int8_t)(a >> 16) * (int)(int8_t)(b >> 16);
  r += (int)(int8_t)(a >> 24) * (int)(int8_t)(b >> 24);
  return r;
#endif
}

// conv1 value with a FIXED fmaf order (must be identical in both kernels).
__device__ __forceinline__ float conv1_val(const float* xs, const float (*w1t)[16],
                                           int c, int y, int x) {
  float h = 0.f;
#pragma unroll
  for (int ky = 0; ky < 3; ++ky)
#pragma unroll
    for (int kx = 0; kx < 3; ++kx)
      h = fmaf(xs[(y + ky) * 28 + (x + kx)], w1t[ky * 3 + kx][c], h);
  return h;
}

__global__ void k_zero(unsigned* p) {
  if (threadIdx.x == 0 && blockIdx.x == 0) p[0] = 0u;
}

// Pass 1: global max(|conv1(x,w1)|) via per-block reduce + atomicMax on bits.
__global__ __launch_bounds__(256) void k_conv1max(const float* __restrict__ x,
                                                  const float* __restrict__ w1,
                                                  unsigned* __restrict__ ws_max) {
  __shared__ float xs[784];
  __shared__ float w1t[9][16];
  __shared__ float wred[4];
  const int img = blockIdx.x;
  const float* xi = x + (size_t)img * 784;
  for (int i = threadIdx.x; i < 784; i += 256) xs[i] = xi[i];
  for (int i = threadIdx.x; i < 144; i += 256) w1t[i % 9][i / 9] = w1[i];
  __syncthreads();

  float m = 0.f;
  for (int o = threadIdx.x; o < 16 * 676; o += 256) {
    const int c = o & 15, pos = o >> 4;
    const int y = pos / 26, xx = pos - y * 26;
    m = fmaxf(m, fabsf(conv1_val(xs, w1t, c, y, xx)));
  }
#pragma unroll
  for (int off = 32; off; off >>= 1) m = fmaxf(m, __shfl_down(m, off, 64));
  if ((threadIdx.x & 63) == 0) wred[threadIdx.x >> 6] = m;
  __syncthreads();
  if (threadIdx.x == 0) {
    float mm = fmaxf(fmaxf(wred[0], wred[1]), fmaxf(wred[2], wred[3]));
    atomicMax(ws_max, __float_as_uint(mm));  // |h| >= 0: bit order == float order
  }
}

// Ternary 3x3 VALID conv over LDS, 16 input channels packed 4 int8/word.
// actw: [H_IN*W_IN][4] words. wgt: [OC][9][4] words. outb: [H_OUT*W_OUT*OC] i8.
template <int H_IN, int W_IN, int OC>
__device__ __forceinline__ void tconv(const int* __restrict__ actw,
                                      const int* __restrict__ wgt,
                                      int8_t* __restrict__ outb) {
  constexpr int H_OUT = H_IN - 2, W_OUT = W_IN - 2;
  constexpr int UNITS = OC * H_OUT;
  const int4* act4 = (const int4*)actw;
  const int4* wgt4 = (const int4*)wgt;
  for (int u = threadIdx.x; u < UNITS; u += 256) {
    const int oc = u % OC;     // consecutive lanes share y -> LDS broadcast
    const int y = u / OC;
    int4 W4[9];
#pragma unroll
    for (int p = 0; p < 9; ++p) W4[p] = wgt4[oc * 9 + p];

    int4 A0[3], A1[3], A2[3];
#pragma unroll
    for (int dy = 0; dy < 3; ++dy) A0[dy] = act4[(y + dy) * W_IN + 0];
#pragma unroll
    for (int dy = 0; dy < 3; ++dy) A1[dy] = act4[(y + dy) * W_IN + 1];

    auto step = [&](const int4* cL, const int4* cM, const int4* cR, int xo) {
      int acc = 0;
#pragma unroll
      for (int dy = 0; dy < 3; ++dy) {
        acc = dot4(cL[dy].x, W4[dy * 3 + 0].x, acc);
        acc = dot4(cL[dy].y, W4[dy * 3 + 0].y, acc);
        acc = dot4(cL[dy].z, W4[dy * 3 + 0].z, acc);
        acc = dot4(cL[dy].w, W4[dy * 3 + 0].w, acc);
        acc = dot4(cM[dy].x, W4[dy * 3 + 1].x, acc);
        acc = dot4(cM[dy].y, W4[dy * 3 + 1].y, acc);
        acc = dot4(cM[dy].z, W4[dy * 3 + 1].z, acc);
        acc = dot4(cM[dy].w, W4[dy * 3 + 1].w, acc);
        acc = dot4(cR[dy].x, W4[dy * 3 + 2].x, acc);
        acc = dot4(cR[dy].y, W4[dy * 3 + 2].y, acc);
        acc = dot4(cR[dy].z, W4[dy * 3 + 2].z, acc);
        acc = dot4(cR[dy].w, W4[dy * 3 + 2].w, acc);
      }
      outb[(y * W_OUT + xo) * OC + oc] = (int8_t)((acc > 0) - (acc < 0));
    };

    int xx = 0;
    for (;;) {
#pragma unroll
      for (int dy = 0; dy < 3; ++dy) A2[dy] = act4[(y + dy) * W_IN + (xx + 2)];
      step(A0, A1, A2, xx);
      if (++xx == W_OUT) break;
#pragma unroll
      for (int dy = 0; dy < 3; ++dy) A0[dy] = act4[(y + dy) * W_IN + (xx + 2)];
      step(A1, A2, A0, xx);
      if (++xx == W_OUT) break;
#pragma unroll
      for (int dy = 0; dy < 3; ++dy) A1[dy] = act4[(y + dy) * W_IN + (xx + 2)];
      step(A2, A0, A1, xx);
      if (++xx == W_OUT) break;
    }
  }
}

__global__ __launch_bounds__(256) void k_forward(
    const float* __restrict__ x, const float* __restrict__ w1,
    const float* __restrict__ w2, const float* __restrict__ w3,
    const float* __restrict__ wfc, const float* __restrict__ bfc,
    const unsigned* __restrict__ ws_max, float* __restrict__ out) {
  __shared__ __align__(16) float xs[784];
  __shared__ float w1t[9][16];
  __shared__ __align__(16) int a1w[676 * 4];   // [26*26][4] words (16 i8 ch)
  __shared__ __align__(16) int h2w[576 * 4];   // [24*24][4]
  __shared__ __align__(16) int h3w[484 * 8];   // [22*22][8] words (32 i8 ch)
  __shared__ __align__(16) int p4w[968];       // 3872 int8 pooled sums (x4)
  __shared__ __align__(16) int w2p[16 * 9 * 4];
  __shared__ __align__(16) int w3p[32 * 9 * 4];
  __shared__ int out_acc[10];

  const int img = blockIdx.x;
  const float* xi = x + (size_t)img * 784;
  for (int i = threadIdx.x; i < 784; i += 256) xs[i] = xi[i];
  for (int i = threadIdx.x; i < 144; i += 256) w1t[i % 9][i / 9] = w1[i];

  // Pack sign(w2): word idx = oc*36 + p*4 + cw, bytes = ic = 4*cw..4*cw+3.
  for (int widx = threadIdx.x; widx < 576; widx += 256) {
    const int oc = widx / 36, r = widx % 36, p = r >> 2, cw = r & 3;
    unsigned wrd = 0;
#pragma unroll
    for (int b = 0; b < 4; ++b) {
      const float v = w2[(oc * 16 + (cw * 4 + b)) * 9 + p];
      const int s = (v > 0.f) - (v < 0.f);
      wrd |= ((unsigned)(uint8_t)(int8_t)s) << (8 * b);
    }
    w2p[widx] = (int)wrd;
  }
  for (int widx = threadIdx.x; widx < 1152; widx += 256) {
    const int oc = widx / 36, r = widx % 36, p = r >> 2, cw = r & 3;
    unsigned wrd = 0;
#pragma unroll
    for (int b = 0; b < 4; ++b) {
      const float v = w3[(oc * 16 + (cw * 4 + b)) * 9 + p];
      const int s = (v > 0.f) - (v < 0.f);
      wrd |= ((unsigned)(uint8_t)(int8_t)s) << (8 * b);
    }
    w3p[widx] = (int)wrd;
  }
  if (threadIdx.x < 10) out_acc[threadIdx.x] = 0;
  __syncthreads();

  // conv1 -> fake-quant sign (ternary). t = h/scale; |t|<=0.5 -> 0 (half-even).
  const float mx = __uint_as_float(*ws_max);
  const float scale = mx / 127.0f + 1e-8f;
  int8_t* a1b = (int8_t*)a1w;
  for (int o = threadIdx.x; o < 16 * 676; o += 256) {
    const int c = o & 15, pos = o >> 4;
    const int y = pos / 26, xx = pos - y * 26;
    const float h = conv1_val(xs, w1t, c, y, xx);
    const float t = h / scale;  //真 f32 division to match reference rounding
    int8_t a = (fabsf(t) <= 0.5f) ? (int8_t)0 : ((t > 0.f) ? (int8_t)1 : (int8_t)-1);
    a1b[pos * 16 + c] = a;
  }
  __syncthreads();

  tconv<26, 26, 16>(a1w, w2p, (int8_t*)h2w);  // -> h2 ternary [24,24,16]
  __syncthreads();
  tconv<24, 24, 32>(h2w, w3p, (int8_t*)h3w);  // -> h3 ternary [22,22,32]
  __syncthreads();

  // avgpool 2x2: keep 4*avg as int8 in flatten order i = c*121 + py*11 + px.
  const int8_t* h3b = (const int8_t*)h3w;
  int8_t* p4b = (int8_t*)p4w;
  for (int i = threadIdx.x; i < 3872; i += 256) {
    const int c = i / 121, yx = i - c * 121;
    const int py = yx / 11, px = yx - py * 11;
    const int y0 = 2 * py, x0 = 2 * px;
    const int s = (int)h3b[(y0 * 22 + x0) * 32 + c] + (int)h3b[(y0 * 22 + x0 + 1) * 32 + c] +
                  (int)h3b[((y0 + 1) * 22 + x0) * 32 + c] + (int)h3b[((y0 + 1) * 22 + x0 + 1) * 32 + c];
    p4b[i] = (int8_t)s;
  }
  __syncthreads();

  // FC: out[j] = 0.25 * sum_i p4[i]*sign(wfc[j,i]) + b[j]. Exact integer path.
  for (int u = threadIdx.x; u < 10 * 121; u += 256) {
    const int j = u / 121, ch = u - j * 121;
    const int base = ch * 32;
    const float4* wrow = (const float4*)(wfc + (size_t)j * 3872 + base);
    int acc = 0;
#pragma unroll
    for (int q = 0; q < 8; ++q) {
      const float4 f = wrow[q];
      const int pw = p4w[(base >> 2) + q];
      acc += ((int)(int8_t)(pw))       * ((f.x > 0.f) - (f.x < 0.f));
      acc += ((int)(int8_t)(pw >> 8))  * ((f.y > 0.f) - (f.y < 0.f));
      acc += ((int)(int8_t)(pw >> 16)) * ((f.z > 0.f) - (f.z < 0.f));
      acc += ((int)(int8_t)(pw >> 24)) * ((f.w > 0.f) - (f.w < 0.f));
    }
    atomicAdd(&out_acc[j], acc);
  }
  __syncthreads();
  if (threadIdx.x < 10)
    out[(size_t)img * 10 + threadIdx.x] = 0.25f * (float)out_acc[threadIdx.x] + bfc[threadIdx.x];
}

extern "C" void kernel_launch(void* const* d_in, const int* in_sizes, int n_in,
                              void* d_out, int out_size, void* d_ws, size_t ws_size,
                              hipStream_t stream) {
  const float* x   = (const float*)d_in[0];
  const float* w1  = (const float*)d_in[1];
  const float* w2  = (const float*)d_in[2];
  const float* w3  = (const float*)d_in[3];
  const float* wfc = (const float*)d_in[4];
  const float* bfc = (const float*)d_in[5];
  float* out = (float*)d_out;
  unsigned* wsmax = (unsigned*)d_ws;
  const int B = in_sizes[0] / 784;

  hipLaunchKernelGGL(k_zero, dim3(1), dim3(64), 0, stream, wsmax);
  hipLaunchKernelGGL(k_conv1max, dim3(B), dim3(256), 0, stream, x, w1, wsmax);
  hipLaunchKernelGGL(k_forward, dim3(B), dim3(256), 0, stream, x, w1, w2, w3,
                     wfc, bfc, wsmax, out);
}

// Round 2
// 569.586 us; speedup vs baseline: 1.4129x; 1.4129x over previous
//
#include <hip/hip_runtime.h>
#include <stdint.h>

// ---------------------------------------------------------------------------
// Binarized QAT CNN forward, fused per-image.
//   conv1 (f32) -> per-tensor int8 fake-quant -> sign  => ternary a1 [26,26,16]
//   conv2(a1, sign(w2)) -> sign                        => ternary h2 [24,(25),16]
//   conv3(h2, sign(w3)) -> sign                        => ternary h3 planar [32][22,22]
//   avgpool2x2 -> p4 (=4*avg, int8, flatten order) -> FC sign(w_fc) + b_fc
// All math after conv1 is exact integer arithmetic; only conv1 + the global
// max (scale) are float-sensitive. conv1 uses one fixed fmaf order in both
// kernels.
//
// R2 changes vs R1 (theory: 18% of cycles were LDS bank conflicts, occ 23%):
//  - h2 rows padded to 25 px (stride 100 words): conv3 act reads / conv2
//    writes go from 4-way conflict (96 % 32 == 0) to conflict-free.
//  - h3 stored planar [oc][y][x] (oc stride 121 words, odd -> bank perm).
//  - LDS phase-union: 50 KB -> ~31.9 KB => 5 blocks/CU (occupancy 23->~37%).
// ---------------------------------------------------------------------------

__device__ __forceinline__ int dot4(int a, int b, int c) {
#if __has_builtin(__builtin_amdgcn_sdot4)
  return __builtin_amdgcn_sdot4(a, b, c, false);
#else
  int r = c;
  r += (int)(int8_t)(a)       * (int)(int8_t)(b);
  r += (int)(int8_t)(a >> 8)  * (int)(int8_t)(b >> 8);
  r += (int)(int8_t)(a >> 16) * (int)(int8_t)(b >> 16);
  r += (int)(int8_t)(a >> 24) * (int)(int8_t)(b >> 24);
  return r;
#endif
}

// conv1 value with a FIXED fmaf order (identical in both kernels).
__device__ __forceinline__ float conv1_val(const float* xs, const float (*w1t)[16],
                                           int c, int y, int x) {
  float h = 0.f;
#pragma unroll
  for (int ky = 0; ky < 3; ++ky)
#pragma unroll
    for (int kx = 0; kx < 3; ++kx)
      h = fmaf(xs[(y + ky) * 28 + (x + kx)], w1t[ky * 3 + kx][c], h);
  return h;
}

__global__ void k_zero(unsigned* p) {
  if (threadIdx.x == 0 && blockIdx.x == 0) p[0] = 0u;
}

// Pass 1: global max(|conv1(x,w1)|) via per-block reduce + atomicMax on bits.
__global__ __launch_bounds__(256) void k_conv1max(const float* __restrict__ x,
                                                  const float* __restrict__ w1,
                                                  unsigned* __restrict__ ws_max) {
  __shared__ float xs[784];
  __shared__ float w1t[9][16];
  __shared__ float wred[4];
  const int img = blockIdx.x;
  const float* xi = x + (size_t)img * 784;
  for (int i = threadIdx.x; i < 784; i += 256) xs[i] = xi[i];
  for (int i = threadIdx.x; i < 144; i += 256) w1t[i % 9][i / 9] = w1[i];
  __syncthreads();

  float m = 0.f;
  for (int o = threadIdx.x; o < 16 * 676; o += 256) {
    const int c = o & 15, pos = o >> 4;
    const int y = pos / 26, xx = pos - y * 26;
    m = fmaxf(m, fabsf(conv1_val(xs, w1t, c, y, xx)));
  }
#pragma unroll
  for (int off = 32; off; off >>= 1) m = fmaxf(m, __shfl_down(m, off, 64));
  if ((threadIdx.x & 63) == 0) wred[threadIdx.x >> 6] = m;
  __syncthreads();
  if (threadIdx.x == 0) {
    float mm = fmaxf(fmaxf(wred[0], wred[1]), fmaxf(wred[2], wred[3]));
    atomicMax(ws_max, __float_as_uint(mm));  // |h| >= 0: bit order == float order
  }
}

// Ternary 3x3 VALID conv over LDS, 16 i8 input channels packed 4/word.
//  H_IN : logical input height == width
//  RS_IN: input row stride in PIXELS (each pixel = 16 bytes = one int4)
//  OC   : output channels
//  OUT_RS: output row stride in pixels
//  PLANAR: false -> outb[(y*OUT_RS+x)*OC+oc]; true -> outb[oc*H_OUT*OUT_RS + y*OUT_RS + x]
template <int H_IN, int RS_IN, int OC, int OUT_RS, bool PLANAR>
__device__ __forceinline__ void tconv(const int* __restrict__ actw,
                                      const int* __restrict__ wgt,
                                      int8_t* __restrict__ outb) {
  constexpr int H_OUT = H_IN - 2, W_OUT = H_IN - 2;
  constexpr int UNITS = OC * H_OUT;
  const int4* act4 = (const int4*)actw;
  const int4* wgt4 = (const int4*)wgt;
  for (int u = threadIdx.x; u < UNITS; u += 256) {
    const int oc = u % OC;  // consecutive lanes share y -> LDS broadcast reads
    const int y = u / OC;
    int4 W4[9];
#pragma unroll
    for (int p = 0; p < 9; ++p) W4[p] = wgt4[oc * 9 + p];

    int4 A0[3], A1[3], A2[3];
#pragma unroll
    for (int dy = 0; dy < 3; ++dy) A0[dy] = act4[(y + dy) * RS_IN + 0];
#pragma unroll
    for (int dy = 0; dy < 3; ++dy) A1[dy] = act4[(y + dy) * RS_IN + 1];

    auto step = [&](const int4* cL, const int4* cM, const int4* cR, int xo) {
      int acc = 0;
#pragma unroll
      for (int dy = 0; dy < 3; ++dy) {
        acc = dot4(cL[dy].x, W4[dy * 3 + 0].x, acc);
        acc = dot4(cL[dy].y, W4[dy * 3 + 0].y, acc);
        acc = dot4(cL[dy].z, W4[dy * 3 + 0].z, acc);
        acc = dot4(cL[dy].w, W4[dy * 3 + 0].w, acc);
        acc = dot4(cM[dy].x, W4[dy * 3 + 1].x, acc);
        acc = dot4(cM[dy].y, W4[dy * 3 + 1].y, acc);
        acc = dot4(cM[dy].z, W4[dy * 3 + 1].z, acc);
        acc = dot4(cM[dy].w, W4[dy * 3 + 1].w, acc);
        acc = dot4(cR[dy].x, W4[dy * 3 + 2].x, acc);
        acc = dot4(cR[dy].y, W4[dy * 3 + 2].y, acc);
        acc = dot4(cR[dy].z, W4[dy * 3 + 2].z, acc);
        acc = dot4(cR[dy].w, W4[dy * 3 + 2].w, acc);
      }
      const int8_t s = (int8_t)((acc > 0) - (acc < 0));
      if (PLANAR)
        outb[oc * (H_OUT * OUT_RS) + y * OUT_RS + xo] = s;
      else
        outb[(y * OUT_RS + xo) * OC + oc] = s;
    };

    int xx = 0;
    for (;;) {
#pragma unroll
      for (int dy = 0; dy < 3; ++dy) A2[dy] = act4[(y + dy) * RS_IN + (xx + 2)];
      step(A0, A1, A2, xx);
      if (++xx == W_OUT) break;
#pragma unroll
      for (int dy = 0; dy < 3; ++dy) A0[dy] = act4[(y + dy) * RS_IN + (xx + 2)];
      step(A1, A2, A0, xx);
      if (++xx == W_OUT) break;
#pragma unroll
      for (int dy = 0; dy < 3; ++dy) A1[dy] = act4[(y + dy) * RS_IN + (xx + 2)];
      step(A2, A0, A1, xx);
      if (++xx == W_OUT) break;
    }
  }
}

// ---------------------------------------------------------------------------
// LDS layout (phase-aliased union, 31936 B total => 5 blocks/CU):
//  R1 [0, 15488):      ph1: xs(3136) @0, w1t(576) @3136, a1(10816) @3712
//                      ph3-4: h3 planar 32*484 = 15488
//  R2 [15488, 25088):  ph2-3: h2 = 24 rows * 25 px * 16 B = 9600
//                      ph4-5: p4(3872) @0, out_acc(40) @3872
//  R3 [25088, 32000):  w2p(2304) @0, w3p(4608) @2304   (persistent)
// ---------------------------------------------------------------------------
__global__ __launch_bounds__(256) void k_forward(
    const float* __restrict__ x, const float* __restrict__ w1,
    const float* __restrict__ w2, const float* __restrict__ w3,
    const float* __restrict__ wfc, const float* __restrict__ bfc,
    const unsigned* __restrict__ ws_max, float* __restrict__ out) {
  __shared__ __align__(16) char smem[32000];

  float* xs = (float*)(smem + 0);                    // [784]
  float(*w1t)[16] = (float(*)[16])(smem + 3136);     // [9][16]
  int* a1w = (int*)(smem + 3712);                    // [676][4] words
  int8_t* h3b = (int8_t*)(smem + 0);                 // planar [32][22*22]
  int* h2w = (int*)(smem + 15488);                   // [24*25][4] words (padded rows)
  int* p4w = (int*)(smem + 15488);                   // 3872 int8 (as 968 words)
  int* out_acc = (int*)(smem + 15488 + 3872);        // [10]
  int* w2p = (int*)(smem + 25088);                   // [16][9][4] words
  int* w3p = (int*)(smem + 25088 + 2304);            // [32][9][4] words

  const int img = blockIdx.x;
  const float* xi = x + (size_t)img * 784;
  for (int i = threadIdx.x; i < 784; i += 256) xs[i] = xi[i];
  for (int i = threadIdx.x; i < 144; i += 256) w1t[i % 9][i / 9] = w1[i];

  // Pack sign(w2)/sign(w3): word idx = oc*36 + p*4 + cw, bytes = ic 4*cw..4*cw+3.
  for (int widx = threadIdx.x; widx < 576; widx += 256) {
    const int oc = widx / 36, r = widx % 36, p = r >> 2, cw = r & 3;
    unsigned wrd = 0;
#pragma unroll
    for (int b = 0; b < 4; ++b) {
      const float v = w2[(oc * 16 + (cw * 4 + b)) * 9 + p];
      const int s = (v > 0.f) - (v < 0.f);
      wrd |= ((unsigned)(uint8_t)(int8_t)s) << (8 * b);
    }
    w2p[widx] = (int)wrd;
  }
  for (int widx = threadIdx.x; widx < 1152; widx += 256) {
    const int oc = widx / 36, r = widx % 36, p = r >> 2, cw = r & 3;
    unsigned wrd = 0;
#pragma unroll
    for (int b = 0; b < 4; ++b) {
      const float v = w3[(oc * 16 + (cw * 4 + b)) * 9 + p];
      const int s = (v > 0.f) - (v < 0.f);
      wrd |= ((unsigned)(uint8_t)(int8_t)s) << (8 * b);
    }
    w3p[widx] = (int)wrd;
  }
  __syncthreads();

  // Phase 1: conv1 -> fake-quant sign (ternary a1). round-half-even: |t|<=0.5 -> 0.
  const float mx = __uint_as_float(*ws_max);
  const float scale = mx / 127.0f + 1e-8f;
  int8_t* a1b = (int8_t*)a1w;
  for (int o = threadIdx.x; o < 16 * 676; o += 256) {
    const int c = o & 15, pos = o >> 4;
    const int y = pos / 26, xx = pos - y * 26;
    const float h = conv1_val(xs, w1t, c, y, xx);
    const float t = h / scale;  // exact f32 division to match reference rounding
    int8_t a = (fabsf(t) <= 0.5f) ? (int8_t)0 : ((t > 0.f) ? (int8_t)1 : (int8_t)-1);
    a1b[pos * 16 + c] = a;
  }
  __syncthreads();

  // Phase 2: conv2 -> h2 ternary, rows padded to 25 px.
  tconv<26, 26, 16, 25, false>(a1w, w2p, (int8_t*)h2w);
  __syncthreads();

  // Phase 3: conv3 -> h3 ternary, planar [oc][22][22] (overwrites xs/w1t/a1: dead).
  tconv<24, 25, 32, 22, true>(h2w, w3p, h3b);
  __syncthreads();

  // Phase 4: avgpool 2x2 -> p4 = 4*avg (int8), flatten order i = c*121 + py*11 + px.
  int8_t* p4b = (int8_t*)p4w;
  for (int i = threadIdx.x; i < 3872; i += 256) {
    const int c = i / 121, yx = i - c * 121;
    const int py = yx / 11, px = yx - py * 11;
    const char* base = (const char*)h3b + c * 484 + (2 * py) * 22 + 2 * px;
    const unsigned short r0 = *(const unsigned short*)(base);       // even addr
    const unsigned short r1 = *(const unsigned short*)(base + 22);  // even addr
    const int s = (int)(int8_t)(r0 & 0xff) + (int)(int8_t)(r0 >> 8) +
                  (int)(int8_t)(r1 & 0xff) + (int)(int8_t)(r1 >> 8);
    p4b[i] = (int8_t)s;
  }
  if (threadIdx.x < 10) out_acc[threadIdx.x] = 0;
  __syncthreads();

  // Phase 5: FC. out[j] = 0.25 * sum_i p4[i]*sign(wfc[j,i]) + b[j]. Exact ints.
  const int4* p44 = (const int4*)p4w;
  for (int u = threadIdx.x; u < 10 * 121; u += 256) {
    const int j = u / 121, ch = u - j * 121;
    const int base = ch * 32;
    const float4* wrow = (const float4*)(wfc + (size_t)j * 3872 + base);
    const int4 pa = p44[ch * 2 + 0];
    const int4 pb = p44[ch * 2 + 1];
    const int pws[8] = {pa.x, pa.y, pa.z, pa.w, pb.x, pb.y, pb.z, pb.w};
    int acc = 0;
#pragma unroll
    for (int q = 0; q < 8; ++q) {
      const float4 f = wrow[q];
      const int pw = pws[q];
      acc += ((int)(int8_t)(pw))       * ((f.x > 0.f) - (f.x < 0.f));
      acc += ((int)(int8_t)(pw >> 8))  * ((f.y > 0.f) - (f.y < 0.f));
      acc += ((int)(int8_t)(pw >> 16)) * ((f.z > 0.f) - (f.z < 0.f));
      acc += ((int)(int8_t)(pw >> 24)) * ((f.w > 0.f) - (f.w < 0.f));
    }
    atomicAdd(&out_acc[j], acc);
  }
  __syncthreads();
  if (threadIdx.x < 10)
    out[(size_t)img * 10 + threadIdx.x] = 0.25f * (float)out_acc[threadIdx.x] + bfc[threadIdx.x];
}

extern "C" void kernel_launch(void* const* d_in, const int* in_sizes, int n_in,
                              void* d_out, int out_size, void* d_ws, size_t ws_size,
                              hipStream_t stream) {
  const float* x   = (const float*)d_in[0];
  const float* w1  = (const float*)d_in[1];
  const float* w2  = (const float*)d_in[2];
  const float* w3  = (const float*)d_in[3];
  const float* wfc = (const float*)d_in[4];
  const float* bfc = (const float*)d_in[5];
  float* out = (float*)d_out;
  unsigned* wsmax = (unsigned*)d_ws;
  const int B = in_sizes[0] / 784;

  hipLaunchKernelGGL(k_zero, dim3(1), dim3(64), 0, stream, wsmax);
  hipLaunchKernelGGL(k_conv1max, dim3(B), dim3(256), 0, stream, x, w1, wsmax);
  hipLaunchKernelGGL(k_forward, dim3(B), dim3(256), 0, stream, x, w1, w2, w3,
                     wfc, bfc, wsmax, out);
}

// Round 3
// 409.642 us; speedup vs baseline: 1.9645x; 1.3904x over previous
//
#include <hip/hip_runtime.h>
#include <stdint.h>

// ---------------------------------------------------------------------------
// Binarized QAT CNN forward, fused per-image (R3: MFMA conv path).
//   conv1 (f32, v_pk_fma) -> fake-quant sign (mult-threshold, no div)
//       => ternary a1, pixel-major i8 [26*26][16]
//   conv2 = implicit GEMM [M=576,N=16,K=144] via mfma_i32_16x16x64_i8
//       => h2 pixel-major i8 [24*24][16]
//   conv3 = implicit GEMM [M=484,N=32,K=144]  => h3 planar i8 [32][22*22]
//   avgpool2x2 -> p4 (=4*avg, int8) -> FC vs precomputed packed sign(w_fc)
// All math after conv1 is exact integer arithmetic. conv1/scale boundary
// behavior is robust (no value lands within ~1 ulp of a rounding boundary).
//
// MFMA i8 16x16x64 fragment mapping (gfx950, extrapolated from verified
// f16/bf16 pattern; C/D mapping HW-verified dtype-independent):
//   A: lane l holds A[m=l&15][k=16*(l>>4)+j], j=0..15 (byte j of 4 dwords)
//   B: lane l holds B[k=16*(l>>4)+j][n=l&15]
//   D: reg r: row=(l>>4)*4+r, col=l&15
// K=144 = 9 pixels x 16ch -> k-block q' = window pixel (ky,kx); 3 MFMA with
// k padded to 192 (blocks 9-11 contribute 0 via zeroed A fragment).
// ---------------------------------------------------------------------------

typedef int int4v __attribute__((ext_vector_type(4)));
typedef float f2 __attribute__((ext_vector_type(2)));

__device__ __forceinline__ int4v mfma_i8(int4v a, int4v b, int4v c) {
  return __builtin_amdgcn_mfma_i32_16x16x64_i8(a, b, c, 0, 0, 0);
}

__device__ __forceinline__ int dot4(int a, int b, int c) {
#if __has_builtin(__builtin_amdgcn_sdot4)
  return __builtin_amdgcn_sdot4(a, b, c, false);
#else
  int r = c;
  r += (int)(int8_t)(a)       * (int)(int8_t)(b);
  r += (int)(int8_t)(a >> 8)  * (int)(int8_t)(b >> 8);
  r += (int)(int8_t)(a >> 16) * (int)(int8_t)(b >> 16);
  r += (int)(int8_t)(a >> 24) * (int)(int8_t)(b >> 24);
  return r;
#endif
}

// Pack sign(w_fc) as int8 into d_ws (+64), and zero the max cell (d_ws+0).
__global__ __launch_bounds__(256) void k_packfc(const float* __restrict__ wfc,
                                                unsigned* __restrict__ ws) {
  if (blockIdx.x == 0 && threadIdx.x == 0) ws[0] = 0u;  // wsmax
  int8_t* sw = (int8_t*)ws + 64;
  const int widx = blockIdx.x * 256 + threadIdx.x;  // word over 10*968
  if (widx < 9680) {
    const float4 f = ((const float4*)wfc)[widx];
    unsigned w = 0;
    w |= ((unsigned)(uint8_t)(int8_t)((f.x > 0.f) - (f.x < 0.f)));
    w |= ((unsigned)(uint8_t)(int8_t)((f.y > 0.f) - (f.y < 0.f))) << 8;
    w |= ((unsigned)(uint8_t)(int8_t)((f.z > 0.f) - (f.z < 0.f))) << 16;
    w |= ((unsigned)(uint8_t)(int8_t)((f.w > 0.f) - (f.w < 0.f))) << 24;
    ((int*)sw)[widx] = (int)w;
  }
}

// Pass 1: global max(|conv1(x,w1)|). Per-pixel threads, 16ch via packed f32.
__global__ __launch_bounds__(256) void k_conv1max(const float* __restrict__ x,
                                                  const float* __restrict__ w1,
                                                  unsigned* __restrict__ ws_max) {
  __shared__ __align__(8) float xs[784];
  __shared__ __align__(8) float w1t[144];  // [tap i][ch c] = w1t[i*16+c]
  __shared__ float wred[4];
  const float* xi = x + (size_t)blockIdx.x * 784;
  for (int i = threadIdx.x; i < 784; i += 256) xs[i] = xi[i];
  if (threadIdx.x < 144) {
    const int c = threadIdx.x / 9, i = threadIdx.x % 9;
    w1t[i * 16 + c] = w1[threadIdx.x];
  }
  __syncthreads();

  const f2* w1t2 = (const f2*)w1t;  // [i][cw] cw=0..7 channel pairs
  float m = 0.f;
  for (int px = threadIdx.x; px < 676; px += 256) {
    const int oy = px / 26, ox = px - oy * 26;
    float xw[9];
#pragma unroll
    for (int r = 0; r < 3; ++r)
#pragma unroll
      for (int cc = 0; cc < 3; ++cc) xw[r * 3 + cc] = xs[(oy + r) * 28 + ox + cc];
#pragma unroll
    for (int cw = 0; cw < 8; ++cw) {
      f2 h = {0.f, 0.f};
#pragma unroll
      for (int i = 0; i < 9; ++i) {
        const f2 s = {xw[i], xw[i]};
        h += w1t2[i * 8 + cw] * s;
      }
      m = fmaxf(m, fmaxf(fabsf(h.x), fabsf(h.y)));
    }
  }
#pragma unroll
  for (int off = 32; off; off >>= 1) m = fmaxf(m, __shfl_down(m, off, 64));
  if ((threadIdx.x & 63) == 0) wred[threadIdx.x >> 6] = m;
  __syncthreads();
  if (threadIdx.x == 0) {
    float mm = fmaxf(fmaxf(wred[0], wred[1]), fmaxf(wred[2], wred[3]));
    atomicMax(ws_max, __float_as_uint(mm));  // bits ordered for floats >= 0
  }
}

// ---------------------------------------------------------------------------
// LDS layout (31616 B => 5 blocks/CU):
//  RegionA [0,15488):  ph1-2: xs(3136)@0, w1t(576)@3136, a1(10816)@3712
//                      ph3-4: h3 planar [32][484]
//  RegionB [15488,24704): ph2-3: h2 [576 px][16] = 9216
//                         ph4-5: p4(3872)@15488, out_acc(40)@19360
//  RegionC [24704,31616): w2m [16][9][16]=2304 @24704, w3m [32][9][16]=4608 @27008
// ---------------------------------------------------------------------------
__global__ __launch_bounds__(256) void k_forward(
    const float* __restrict__ x, const float* __restrict__ w1,
    const float* __restrict__ w2, const float* __restrict__ w3,
    const int* __restrict__ sw,   // packed sign(w_fc), [10][968] words
    const float* __restrict__ bfc,
    const unsigned* __restrict__ ws_max, float* __restrict__ out) {
  __shared__ __align__(16) char smem[31616];
  float* xs = (float*)(smem);
  float* w1t = (float*)(smem + 3136);
  int8_t* a1b = (int8_t*)(smem + 3712);
  int8_t* h3b = (int8_t*)(smem);
  int8_t* h2b = (int8_t*)(smem + 15488);
  int* p4w = (int*)(smem + 15488);
  int* out_acc = (int*)(smem + 19360);
  int8_t* w2m = (int8_t*)(smem + 24704);
  int8_t* w3m = (int8_t*)(smem + 27008);

  const int tid = threadIdx.x;
  const float* xi = x + (size_t)blockIdx.x * 784;
  for (int i = tid; i < 784; i += 256) xs[i] = xi[i];
  if (tid < 144) w1t[(tid % 9) * 16 + (tid / 9)] = w1[tid];

  // Pack sign(w2)/sign(w3) as i8: layout [oc][p][ic], word = oc*36 + p*4 + icg.
  for (int widx = tid; widx < 576; widx += 256) {
    const int oc = widx / 36, r = widx % 36, p = r >> 2, icg = r & 3;
    unsigned wrd = 0;
#pragma unroll
    for (int b = 0; b < 4; ++b) {
      const float v = w2[(oc * 16 + (icg * 4 + b)) * 9 + p];
      wrd |= ((unsigned)(uint8_t)(int8_t)((v > 0.f) - (v < 0.f))) << (8 * b);
    }
    ((int*)w2m)[widx] = (int)wrd;
  }
  for (int widx = tid; widx < 1152; widx += 256) {
    const int oc = widx / 36, r = widx % 36, p = r >> 2, icg = r & 3;
    unsigned wrd = 0;
#pragma unroll
    for (int b = 0; b < 4; ++b) {
      const float v = w3[(oc * 16 + (icg * 4 + b)) * 9 + p];
      wrd |= ((unsigned)(uint8_t)(int8_t)((v > 0.f) - (v < 0.f))) << (8 * b);
    }
    ((int*)w3m)[widx] = (int)wrd;
  }
  __syncthreads();

  // Phase 1: conv1 -> ternary a1, pixel-major [px][16] i8.
  const float scale = __uint_as_float(*ws_max) / 127.0f + 1e-8f;
  const float thr = 0.5f * scale;
  const f2* w1t2 = (const f2*)w1t;
  for (int px = tid; px < 676; px += 256) {
    const int oy = px / 26, ox = px - oy * 26;
    float xw[9];
#pragma unroll
    for (int r = 0; r < 3; ++r)
#pragma unroll
      for (int cc = 0; cc < 3; ++cc) xw[r * 3 + cc] = xs[(oy + r) * 28 + ox + cc];
    unsigned wq[4] = {0u, 0u, 0u, 0u};
#pragma unroll
    for (int cw = 0; cw < 8; ++cw) {
      f2 h = {0.f, 0.f};
#pragma unroll
      for (int i = 0; i < 9; ++i) {
        const f2 s = {xw[i], xw[i]};
        h += w1t2[i * 8 + cw] * s;
      }
      const int a0 = (h.x > thr) - (h.x < -thr);
      const int a1s = (h.y > thr) - (h.y < -thr);
      wq[cw >> 1] |= ((unsigned)(uint8_t)(int8_t)a0) << (8 * ((2 * cw) & 3));
      wq[cw >> 1] |= ((unsigned)(uint8_t)(int8_t)a1s) << (8 * ((2 * cw + 1) & 3));
    }
    *(int4*)(a1b + px * 16) = make_int4((int)wq[0], (int)wq[1], (int)wq[2], (int)wq[3]);
  }
  __syncthreads();

  // MFMA lane geometry (shared by conv2/conv3).
  const int lane = tid & 63, wv = tid >> 6;
  const int col = lane & 15, quad = lane >> 4;
  int offA2[3], offA3[3], offB[3];
#pragma unroll
  for (int t = 0; t < 3; ++t) {
    const int qp = t * 4 + quad;          // window-pixel k-block (0..11)
    const int ky = qp / 3, kx = qp - 3 * ky;
    offA2[t] = (ky * 26 + kx) * 16;       // a1 row stride 26 px
    offA3[t] = (ky * 24 + kx) * 16;       // h2 row stride 24 px
    offB[t] = qp * 16;
  }
  const bool ok2 = (quad == 0);           // t=2: only q'=8 is a real k-block

  // Phase 2: conv2 via MFMA, 36 m-tiles, N=16.
  {
    const int8_t* wb = w2m + col * 144;
    for (int mt = wv; mt < 36; mt += 4) {
      const int pA = mt * 16 + col;
      const int oy = pA / 24, ox = pA - oy * 24;
      const int8_t* abase = a1b + (oy * 26 + ox) * 16;
      int4v acc = {0, 0, 0, 0};
      acc = mfma_i8(*(const int4v*)(abase + offA2[0]), *(const int4v*)(wb + offB[0]), acc);
      acc = mfma_i8(*(const int4v*)(abase + offA2[1]), *(const int4v*)(wb + offB[1]), acc);
      int4v a2 = *(const int4v*)(abase + offA2[2]);   // OOB-in-smem garbage ok
      if (!ok2) a2 = (int4v){0, 0, 0, 0};             // zero A => contributes 0
      acc = mfma_i8(a2, *(const int4v*)(wb + offB[2]), acc);
      const int pxb = mt * 16 + quad * 4;
#pragma unroll
      for (int r = 0; r < 4; ++r) {
        const int v = acc[r];
        h2b[(pxb + r) * 16 + col] = (int8_t)((v > 0) - (v < 0));
      }
    }
  }
  __syncthreads();

  // Phase 3: conv3 via MFMA, 31 m-tiles x 2 n-tiles, N=32. h3 planar [oc][484].
  {
    for (int ti = wv; ti < 62; ti += 4) {
      const int mt = ti >> 1, nt = ti & 1;
      int pA = mt * 16 + col;
      if (pA > 483) pA = 483;  // clamp partial tile (results discarded)
      const int oy = pA / 22, ox = pA - oy * 22;
      const int8_t* abase = h2b + (oy * 24 + ox) * 16;
      const int8_t* wb = w3m + (nt * 16 + col) * 144;
      int4v acc = {0, 0, 0, 0};
      acc = mfma_i8(*(const int4v*)(abase + offA3[0]), *(const int4v*)(wb + offB[0]), acc);
      acc = mfma_i8(*(const int4v*)(abase + offA3[1]), *(const int4v*)(wb + offB[1]), acc);
      int4v a2 = *(const int4v*)(abase + offA3[2]);
      if (!ok2) a2 = (int4v){0, 0, 0, 0};
      acc = mfma_i8(a2, *(const int4v*)(wb + offB[2]), acc);
      const int oc = nt * 16 + col;
      const int pxb = mt * 16 + quad * 4;
#pragma unroll
      for (int r = 0; r < 4; ++r) {
        const int px = pxb + r;
        const int v = acc[r];
        if (px < 484) h3b[oc * 484 + px] = (int8_t)((v > 0) - (v < 0));
      }
    }
  }
  __syncthreads();

  // Phase 4: avgpool 2x2 -> p4 = 4*avg (int8), flatten order i = c*121+py*11+px.
  int8_t* p4b = (int8_t*)p4w;
  for (int i = tid; i < 3872; i += 256) {
    const int c = i / 121, yx = i - c * 121;
    const int py = yx / 11, px = yx - py * 11;
    const char* base = (const char*)h3b + c * 484 + (2 * py) * 22 + 2 * px;
    const unsigned short r0 = *(const unsigned short*)(base);
    const unsigned short r1 = *(const unsigned short*)(base + 22);
    const int s = (int)(int8_t)(r0 & 0xff) + (int)(int8_t)(r0 >> 8) +
                  (int)(int8_t)(r1 & 0xff) + (int)(int8_t)(r1 >> 8);
    p4b[i] = (int8_t)s;
  }
  if (tid < 10) out_acc[tid] = 0;
  __syncthreads();

  // Phase 5: FC vs packed sign(w_fc) from global (L2-resident broadcast).
  for (int u = tid; u < 10 * 121; u += 256) {
    const int j = u / 121, ch = u - j * 121;
    const int* swr = sw + j * 968 + ch * 8;
    const int4 wa = *(const int4*)(swr);
    const int4 wbv = *(const int4*)(swr + 4);
    const int4 pa = ((const int4*)p4w)[ch * 2 + 0];
    const int4 pb = ((const int4*)p4w)[ch * 2 + 1];
    int acc = 0;
    acc = dot4(pa.x, wa.x, acc);
    acc = dot4(pa.y, wa.y, acc);
    acc = dot4(pa.z, wa.z, acc);
    acc = dot4(pa.w, wa.w, acc);
    acc = dot4(pb.x, wbv.x, acc);
    acc = dot4(pb.y, wbv.y, acc);
    acc = dot4(pb.z, wbv.z, acc);
    acc = dot4(pb.w, wbv.w, acc);
    atomicAdd(&out_acc[j], acc);
  }
  __syncthreads();
  if (tid < 10)
    out[(size_t)blockIdx.x * 10 + tid] = 0.25f * (float)out_acc[tid] + bfc[tid];
}

extern "C" void kernel_launch(void* const* d_in, const int* in_sizes, int n_in,
                              void* d_out, int out_size, void* d_ws, size_t ws_size,
                              hipStream_t stream) {
  const float* x   = (const float*)d_in[0];
  const float* w1  = (const float*)d_in[1];
  const float* w2  = (const float*)d_in[2];
  const float* w3  = (const float*)d_in[3];
  const float* wfc = (const float*)d_in[4];
  const float* bfc = (const float*)d_in[5];
  float* out = (float*)d_out;
  unsigned* wsu = (unsigned*)d_ws;
  const int* sw = (const int*)((const char*)d_ws + 64);
  const int B = in_sizes[0] / 784;

  hipLaunchKernelGGL(k_packfc, dim3(38), dim3(256), 0, stream, wfc, wsu);
  hipLaunchKernelGGL(k_conv1max, dim3(B), dim3(256), 0, stream, x, w1, wsu);
  hipLaunchKernelGGL(k_forward, dim3(B), dim3(256), 0, stream, x, w1, w2, w3,
                     sw, bfc, wsu, out);
}

// Round 4
// 351.057 us; speedup vs baseline: 2.2924x; 1.1669x over previous
//
#include <hip/hip_runtime.h>
#include <stdint.h>

// ---------------------------------------------------------------------------
// Binarized QAT CNN forward, fused per-image (R4).
//   conv1 (f32 pk-fma) -> fake-quant sign => ternary a1 pixel-major [676][16] i8
//   conv2: MFMA D = sign(w2)[16x144] x a1patches[144x16px]  (A=weights!)
//          => h2 pixel-major [576][16] i8 (+-1), packed dword stores
//   conv3: MFMA D = sign(w3)[32x144] x h2patches => h3 [484 px][32 ch], 0..2 enc
//   pool:  word-adds (no cross-byte carry) -> p4 n=s+4 in [121 pos][48B pad]
//   FC:    dot4 vs precomputed sign(w_fc) in [j][pos][ch] order; out = 0.25*acc
//          + badj[j]   (badj = b_fc - rowsum(sign w_fc) corrects the +1 bias)
// All post-conv1 math is exact integer. Weight packing + FC rowsums hoisted
// to per-launch prep kernels (d_ws is re-poisoned every call, so re-run).
//
// MFMA i8 16x16x64 lane mapping (gfx950): A: lane l holds A[m=l&15][k=16q+j];
// B: B[k=16q+j][n=l&15]; D reg r: row=(l>>4)*4+r, col=l&15.  With A=weights,
// row=oc, col=pixel -> lane's 4 D values are 4 consecutive channels of one
// pixel -> one packed u32 store. K=144 padded to 192 by zeroing the WEIGHT
// fragment for k-blocks 9..11 (zero A kills garbage B reads).
//
// d_ws layout: [0] u32 wsmax | [64] float badj[10] | [128] w2m 576 dw |
//              [2432] w3m 1152 dw | [7040] sw 9680 dw  (total 45760 B)
// ---------------------------------------------------------------------------

typedef int int4v __attribute__((ext_vector_type(4)));
typedef float f2 __attribute__((ext_vector_type(2)));

__device__ __forceinline__ int4v mfma_i8(int4v a, int4v b, int4v c) {
  return __builtin_amdgcn_mfma_i32_16x16x64_i8(a, b, c, 0, 0, 0);
}

__device__ __forceinline__ int dot4(int a, int b, int c) {
#if __has_builtin(__builtin_amdgcn_sdot4)
  return __builtin_amdgcn_sdot4(a, b, c, false);
#else
  int r = c;
  r += (int)(int8_t)(a)       * (int)(int8_t)(b);
  r += (int)(int8_t)(a >> 8)  * (int)(int8_t)(b >> 8);
  r += (int)(int8_t)(a >> 16) * (int)(int8_t)(b >> 16);
  r += (int)(int8_t)(a >> 24) * (int)(int8_t)(b >> 24);
  return r;
#endif
}

__device__ __forceinline__ int sgn_pack_byte(float v) {
  return (v > 0.f) - (v < 0.f);
}

// 10 blocks: block j computes badj[j] = bfc[j] - sum_i sign(wfc[j,i]).
// Block 0 also zeroes wsmax.
__global__ __launch_bounds__(256) void k_prep(const float* __restrict__ wfc,
                                              const float* __restrict__ bfc,
                                              unsigned* __restrict__ ws) {
  __shared__ int part[4];
  const int j = blockIdx.x;
  int s = 0;
  for (int i = threadIdx.x; i < 3872; i += 256) {
    const float v = wfc[j * 3872 + i];
    s += (v > 0.f) - (v < 0.f);
  }
#pragma unroll
  for (int off = 32; off; off >>= 1) s += __shfl_down(s, off, 64);
  if ((threadIdx.x & 63) == 0) part[threadIdx.x >> 6] = s;
  __syncthreads();
  if (threadIdx.x == 0) {
    const int rs = part[0] + part[1] + part[2] + part[3];
    ((float*)ws)[16 + j] = bfc[j] - (float)rs;  // badj @ byte 64
  }
  if (blockIdx.x == 0 && threadIdx.x == 64) ws[0] = 0u;  // wsmax
}

// 45 blocks: pack sign(w2), sign(w3) in MFMA-A layout and sign(w_fc) in
// [j][pos][ch-word] order into d_ws.
__global__ __launch_bounds__(256) void k_packfc(const float* __restrict__ w2,
                                                const float* __restrict__ w3,
                                                const float* __restrict__ wfc,
                                                unsigned* __restrict__ ws) {
  int* dst = (int*)((char*)ws + 128);
  const int widx = blockIdx.x * 256 + threadIdx.x;
  if (widx < 576) {  // w2m: dword = oc*36 + wp*4 + icg
    const int oc = widx / 36, r = widx % 36, wp = r >> 2, icg = r & 3;
    unsigned wrd = 0;
#pragma unroll
    for (int b = 0; b < 4; ++b) {
      const float v = w2[(oc * 16 + icg * 4 + b) * 9 + wp];
      wrd |= ((unsigned)(uint8_t)(int8_t)sgn_pack_byte(v)) << (8 * b);
    }
    dst[widx] = (int)wrd;
  } else if (widx < 1728) {  // w3m
    const int t = widx - 576;
    const int oc = t / 36, r = t % 36, wp = r >> 2, icg = r & 3;
    unsigned wrd = 0;
#pragma unroll
    for (int b = 0; b < 4; ++b) {
      const float v = w3[(oc * 16 + icg * 4 + b) * 9 + wp];
      wrd |= ((unsigned)(uint8_t)(int8_t)sgn_pack_byte(v)) << (8 * b);
    }
    dst[widx] = (int)wrd;
  } else if (widx < 11408) {  // sw: dword = j*968 + pos*8 + cg, byte b: c=4cg+b
    const int t = widx - 1728;
    const int j = t / 968, r = t % 968, pos = r >> 3, cg = r & 7;
    unsigned wrd = 0;
#pragma unroll
    for (int b = 0; b < 4; ++b) {
      const float v = wfc[j * 3872 + (cg * 4 + b) * 121 + pos];
      wrd |= ((unsigned)(uint8_t)(int8_t)sgn_pack_byte(v)) << (8 * b);
    }
    dst[widx] = (int)wrd;
  }
}

// Global max(|conv1|): 16 images per block => 512 blocks, 512 atomics.
__global__ __launch_bounds__(256) void k_conv1max(const float* __restrict__ x,
                                                  const float* __restrict__ w1,
                                                  unsigned* __restrict__ ws_max,
                                                  int B) {
  __shared__ __align__(8) float xs[784];
  __shared__ __align__(8) float w1t[144];
  __shared__ float wred[4];
  if (threadIdx.x < 144) w1t[(threadIdx.x % 9) * 16 + (threadIdx.x / 9)] = w1[threadIdx.x];

  const f2* w1t2 = (const f2*)w1t;
  float m = 0.f;
  const int im0 = blockIdx.x * 16;
  const int im1 = (im0 + 16 < B) ? im0 + 16 : B;
  for (int im = im0; im < im1; ++im) {
    __syncthreads();  // protect xs from previous iteration's readers
    const float* xi = x + (size_t)im * 784;
    for (int i = threadIdx.x; i < 784; i += 256) xs[i] = xi[i];
    __syncthreads();
    for (int px = threadIdx.x; px < 676; px += 256) {
      const int oy = px / 26, ox = px - oy * 26;
      float xw[9];
#pragma unroll
      for (int r = 0; r < 3; ++r)
#pragma unroll
        for (int cc = 0; cc < 3; ++cc) xw[r * 3 + cc] = xs[(oy + r) * 28 + ox + cc];
#pragma unroll
      for (int cw = 0; cw < 8; ++cw) {
        f2 h = {0.f, 0.f};
#pragma unroll
        for (int i = 0; i < 9; ++i) {
          const f2 s = {xw[i], xw[i]};
          h += w1t2[i * 8 + cw] * s;
        }
        m = fmaxf(m, fmaxf(fabsf(h.x), fabsf(h.y)));
      }
    }
  }
#pragma unroll
  for (int off = 32; off; off >>= 1) m = fmaxf(m, __shfl_down(m, off, 64));
  if ((threadIdx.x & 63) == 0) wred[threadIdx.x >> 6] = m;
  __syncthreads();
  if (threadIdx.x == 0) {
    const float mm = fmaxf(fmaxf(wred[0], wred[1]), fmaxf(wred[2], wred[3]));
    atomicMax(ws_max, __float_as_uint(mm));
  }
}

// ---------------------------------------------------------------------------
// k_forward LDS (31616 B => 5 blocks/CU by LDS; VGPR-capped 4 by bounds):
//  [0,15488):     ph1-2: xs(3136)@0 w1t(576)@3136 a1(10816)@3712
//                 ph3-4: h3 [484 px][32 ch] 0..2-encoded
//  [15488,24704): ph2-3: h2 [576 px][16 ch] +-1
//                 ph4-5: p4 [121][48B] n-bytes @15488; out_acc[10] @21296
//  [24704,31616): w2m(2304) w3m(4608)  (loaded coalesced from d_ws)
// ---------------------------------------------------------------------------
__global__ __launch_bounds__(256, 4) void k_forward(
    const float* __restrict__ x, const float* __restrict__ w1,
    const int* __restrict__ wpack,   // d_ws+128: w2m(576) | w3m(1152)
    const int* __restrict__ sw,      // d_ws+7040: [10][968] words
    const float* __restrict__ badj,  // d_ws+64: [10]
    const unsigned* __restrict__ ws_max, float* __restrict__ out) {
  __shared__ __align__(16) char smem[31616];
  float* xs = (float*)(smem);
  float* w1t = (float*)(smem + 3136);
  int8_t* a1b = (int8_t*)(smem + 3712);
  int* h3w = (int*)(smem);             // [484][8] dwords
  int* h2w = (int*)(smem + 15488);     // [576][4] dwords
  int* p4w = (int*)(smem + 15488);     // [121][12] dwords (48 B padded)
  int* out_acc = (int*)(smem + 21296);
  int* wlds = (int*)(smem + 24704);    // w2m(576) | w3m(1152)
  const int8_t* w2m = (const int8_t*)wlds;
  const int8_t* w3m = (const int8_t*)(wlds + 576);

  const int tid = threadIdx.x;
  const float* xi = x + (size_t)blockIdx.x * 784;
  for (int i = tid; i < 784; i += 256) xs[i] = xi[i];
  if (tid < 144) w1t[(tid % 9) * 16 + (tid / 9)] = w1[tid];
  for (int i = tid; i < 1728; i += 256) wlds[i] = wpack[i];  // coalesced
  __syncthreads();

  // Phase 1: conv1 -> ternary a1 pixel-major.
  const float scale = __uint_as_float(*ws_max) / 127.0f + 1e-8f;
  const float thr = 0.5f * scale;
  const f2* w1t2 = (const f2*)w1t;
  for (int px = tid; px < 676; px += 256) {
    const int oy = px / 26, ox = px - oy * 26;
    float xw[9];
#pragma unroll
    for (int r = 0; r < 3; ++r)
#pragma unroll
      for (int cc = 0; cc < 3; ++cc) xw[r * 3 + cc] = xs[(oy + r) * 28 + ox + cc];
    unsigned wq[4] = {0u, 0u, 0u, 0u};
#pragma unroll
    for (int cw = 0; cw < 8; ++cw) {
      f2 h = {0.f, 0.f};
#pragma unroll
      for (int i = 0; i < 9; ++i) {
        const f2 s = {xw[i], xw[i]};
        h += w1t2[i * 8 + cw] * s;
      }
      const int a0 = (h.x > thr) - (h.x < -thr);
      const int a1s = (h.y > thr) - (h.y < -thr);
      wq[cw >> 1] |= ((unsigned)(uint8_t)(int8_t)a0) << (8 * ((2 * cw) & 3));
      wq[cw >> 1] |= ((unsigned)(uint8_t)(int8_t)a1s) << (8 * ((2 * cw + 1) & 3));
    }
    *(int4*)(a1b + px * 16) = make_int4((int)wq[0], (int)wq[1], (int)wq[2], (int)wq[3]);
  }
  __syncthreads();

  // MFMA lane geometry.
  const int lane = tid & 63, wv = tid >> 6;
  const int col = lane & 15, quad = lane >> 4;
  int dAct2[3], dAct3[3];
#pragma unroll
  for (int t = 0; t < 3; ++t) {
    const int wp = t * 4 + quad;  // window pixel (k-block); wp>8 dead (A zeroed)
    dAct2[t] = ((wp / 3) * 26 + wp % 3) * 16;
    dAct3[t] = ((wp / 3) * 24 + wp % 3) * 16;
  }
  const bool kq0 = (quad == 0);  // t=2: only wp=8 is a real k-block

  // Phase 2: conv2. A=sign(w2) frags in regs; 36 n-tiles of 16 pixels.
  {
    const int8_t* wb = w2m + col * 144;  // lane's oc = col
    int4v WA[3];
    WA[0] = *(const int4v*)(wb + (quad * 16));
    WA[1] = *(const int4v*)(wb + ((4 + quad) * 16));
    WA[2] = kq0 ? *(const int4v*)(wb + 128) : (int4v){0, 0, 0, 0};
    for (int nt = wv; nt < 36; nt += 4) {
      const int p = nt * 16 + col;  // output pixel (col = n)
      const int oy = p / 24, ox = p - oy * 24;
      const int8_t* abase = a1b + (oy * 26 + ox) * 16;
      int4v acc = {0, 0, 0, 0};
      acc = mfma_i8(WA[0], *(const int4v*)(abase + dAct2[0]), acc);
      acc = mfma_i8(WA[1], *(const int4v*)(abase + dAct2[1]), acc);
      acc = mfma_i8(WA[2], *(const int4v*)(abase + dAct2[2]), acc);
      // Lane holds channels 4*quad..4*quad+3 of pixel p -> one dword.
      unsigned pk = 0;
#pragma unroll
      for (int r = 0; r < 4; ++r) {
        const int v = acc[r];
        pk |= ((unsigned)(uint8_t)(int8_t)((v > 0) - (v < 0))) << (8 * r);
      }
      h2w[p * 4 + quad] = (int)pk;  // 64 consecutive dwords: conflict-free
    }
  }
  __syncthreads();

  // Phase 3: conv3. A=sign(w3) frags (2 oc-tiles) in regs; 31 px-tiles.
  {
    int4v WA[2][3];
#pragma unroll
    for (int ot = 0; ot < 2; ++ot) {
      const int8_t* wb = w3m + (ot * 16 + col) * 144;
      WA[ot][0] = *(const int4v*)(wb + (quad * 16));
      WA[ot][1] = *(const int4v*)(wb + ((4 + quad) * 16));
      WA[ot][2] = kq0 ? *(const int4v*)(wb + 128) : (int4v){0, 0, 0, 0};
    }
    for (int pt = wv; pt < 31; pt += 4) {
      const int p = pt * 16 + col;
      const int pc = (p < 484) ? p : 483;  // clamp reads for partial tile
      const int oy = pc / 22, ox = pc - oy * 22;
      const int8_t* abase = (const int8_t*)h2w + (oy * 24 + ox) * 16;
      const int4v B0 = *(const int4v*)(abase + dAct3[0]);
      const int4v B1 = *(const int4v*)(abase + dAct3[1]);
      const int4v B2 = *(const int4v*)(abase + dAct3[2]);
#pragma unroll
      for (int ot = 0; ot < 2; ++ot) {
        int4v acc = {0, 0, 0, 0};
        acc = mfma_i8(WA[ot][0], B0, acc);
        acc = mfma_i8(WA[ot][1], B1, acc);
        acc = mfma_i8(WA[ot][2], B2, acc);
        unsigned pk = 0;  // 0..2 encoding (sign+1)
#pragma unroll
        for (int r = 0; r < 4; ++r) {
          const int v = acc[r];
          pk |= ((unsigned)((v > 0) - (v < 0) + 1)) << (8 * r);
        }
        if (p < 484) h3w[p * 8 + ot * 4 + quad] = (int)pk;
      }
    }
  }
  if (tid < 10) out_acc[tid] = 0;
  __syncthreads();

  // Phase 4: avgpool via word adds. bytes <=2 each, sums <=8: no carry.
  for (int u = tid; u < 968; u += 256) {
    const int pos = u >> 3, cg = u & 7;
    const int py = pos / 11, px = pos - py * 11;
    const int base = ((2 * py) * 22 + 2 * px) * 8 + cg;
    const int n4 = h3w[base] + h3w[base + 8] + h3w[base + 176] + h3w[base + 184];
    p4w[pos * 12 + cg] = n4;  // n = s+4 per byte, [121][48B-padded]
  }
  __syncthreads();

  // Phase 5: FC. acc = sum n*sw = true_acc4 + 4*rowsum(sw); badj corrects.
  if (tid < 250) {
    const int j = tid / 25, k = tid % 25;
    const int4* p44 = (const int4*)p4w;
    int acc = 0;
    for (int pos = k; pos < 121; pos += 25) {
      const int4 pa = p44[pos * 3];
      const int4 pb = p44[pos * 3 + 1];
      const int* swr = sw + j * 968 + pos * 8;
      const int4 wa = *(const int4*)(swr);
      const int4 wbv = *(const int4*)(swr + 4);
      acc = dot4(pa.x, wa.x, acc);
      acc = dot4(pa.y, wa.y, acc);
      acc = dot4(pa.z, wa.z, acc);
      acc = dot4(pa.w, wa.w, acc);
      acc = dot4(pb.x, wbv.x, acc);
      acc = dot4(pb.y, wbv.y, acc);
      acc = dot4(pb.z, wbv.z, acc);
      acc = dot4(pb.w, wbv.w, acc);
    }
    atomicAdd(&out_acc[j], acc);
  }
  __syncthreads();
  if (tid < 10)
    out[(size_t)blockIdx.x * 10 + tid] = 0.25f * (float)out_acc[tid] + badj[tid];
}

extern "C" void kernel_launch(void* const* d_in, const int* in_sizes, int n_in,
                              void* d_out, int out_size, void* d_ws, size_t ws_size,
                              hipStream_t stream) {
  const float* x   = (const float*)d_in[0];
  const float* w1  = (const float*)d_in[1];
  const float* w2  = (const float*)d_in[2];
  const float* w3  = (const float*)d_in[3];
  const float* wfc = (const float*)d_in[4];
  const float* bfc = (const float*)d_in[5];
  float* out = (float*)d_out;
  unsigned* wsu = (unsigned*)d_ws;
  const int* wpack = (const int*)((const char*)d_ws + 128);
  const int* sw = (const int*)((const char*)d_ws + 7040);
  const float* badj = (const float*)((const char*)d_ws + 64);
  const int B = in_sizes[0] / 784;

  hipLaunchKernelGGL(k_prep, dim3(10), dim3(256), 0, stream, wfc, bfc, wsu);
  hipLaunchKernelGGL(k_packfc, dim3(45), dim3(256), 0, stream, w2, w3, wfc, wsu);
  hipLaunchKernelGGL(k_conv1max, dim3((B + 15) / 16), dim3(256), 0, stream, x, w1, wsu, B);
  hipLaunchKernelGGL(k_forward, dim3(B), dim3(256), 0, stream, x, w1, wpack, sw,
                     badj, wsu, out);
}

// Round 5
// 272.803 us; speedup vs baseline: 2.9499x; 1.2869x over previous
//
#include <hip/hip_runtime.h>
#include <stdint.h>

// ---------------------------------------------------------------------------
// Binarized QAT CNN forward, fused per-image (R5).
//   conv1 (f32 pk-fma) -> fake-quant sign => ternary a1 pixel-major [676][16] i8
//   conv2: MFMA D = sign(w2)[16x144] x a1patches[144x16px]  (A=weights)
//          => h2 pixel-major [576][16] i8 (+-1), packed dword stores
//   conv3: MFMA D = sign(w3)[32x144] x h2patches => h3 [484 px][32 ch], 0..2 enc
//   pool:  word-adds (no cross-byte carry) -> p4 n=s+4 in [121 pos][48B pad]
//   FC:    dot4 vs precomputed sign(w_fc) in [j][pos][ch] order; out = 0.25*acc
//          + badj[j]   (badj = b_fc - rowsum(sign w_fc) corrects the +1 bias)
//
// R5 vs R4: __launch_bounds__(256) WITHOUT the min-waves arg. R4's (256,4)
// capped arch-VGPRs at 64 (unified-file split with AGPRs) and spilled ~50
// dwords/thread -> 426 MB/dispatch scratch writes (spill-BW-bound, 2.9 TB/s).
// R3 proved this kernel fits in 92 VGPR with no spill. Also merged the two
// prep kernels and widened k_conv1max parallelism (8 img/block).
//
// MFMA i8 16x16x64 lane mapping (gfx950): A: lane l holds A[m=l&15][k=16q+j];
// B: B[k=16q+j][n=l&15]; D reg r: row=(l>>4)*4+r, col=l&15.  With A=weights,
// row=oc, col=pixel -> lane's 4 D values are 4 consecutive channels of one
// pixel -> one packed u32 store. K=144 padded to 192 by zeroing the WEIGHT
// fragment for k-blocks 9..11 (zero A kills garbage B reads).
//
// d_ws layout: [0] u32 wsmax | [64] float badj[10] | [128] w2m 576 dw |
//              [2432] w3m 1152 dw | [7040] sw 9680 dw  (total 45760 B)
// ---------------------------------------------------------------------------

typedef int int4v __attribute__((ext_vector_type(4)));
typedef float f2 __attribute__((ext_vector_type(2)));

__device__ __forceinline__ int4v mfma_i8(int4v a, int4v b, int4v c) {
  return __builtin_amdgcn_mfma_i32_16x16x64_i8(a, b, c, 0, 0, 0);
}

__device__ __forceinline__ int dot4(int a, int b, int c) {
#if __has_builtin(__builtin_amdgcn_sdot4)
  return __builtin_amdgcn_sdot4(a, b, c, false);
#else
  int r = c;
  r += (int)(int8_t)(a)       * (int)(int8_t)(b);
  r += (int)(int8_t)(a >> 8)  * (int)(int8_t)(b >> 8);
  r += (int)(int8_t)(a >> 16) * (int)(int8_t)(b >> 16);
  r += (int)(int8_t)(a >> 24) * (int)(int8_t)(b >> 24);
  return r;
#endif
}

__device__ __forceinline__ int sgn_pack_byte(float v) {
  return (v > 0.f) - (v < 0.f);
}

// Merged prep, 56 blocks:
//  blocks 0..9:  badj[j] = bfc[j] - rowsum(sign(wfc[j,:])); block0 zeroes wsmax
//  blocks 10..55: pack sign(w2), sign(w3) (MFMA-A layout) and sign(w_fc)
//                 ([j][pos][ch-word] order) into d_ws.
__global__ __launch_bounds__(256) void k_prep(const float* __restrict__ w2,
                                              const float* __restrict__ w3,
                                              const float* __restrict__ wfc,
                                              const float* __restrict__ bfc,
                                              unsigned* __restrict__ ws) {
  if (blockIdx.x < 10) {
    __shared__ int part[4];
    const int j = blockIdx.x;
    int s = 0;
    for (int i = threadIdx.x; i < 3872; i += 256) {
      const float v = wfc[j * 3872 + i];
      s += (v > 0.f) - (v < 0.f);
    }
#pragma unroll
    for (int off = 32; off; off >>= 1) s += __shfl_down(s, off, 64);
    if ((threadIdx.x & 63) == 0) part[threadIdx.x >> 6] = s;
    __syncthreads();
    if (threadIdx.x == 0) {
      const int rs = part[0] + part[1] + part[2] + part[3];
      ((float*)ws)[16 + j] = bfc[j] - (float)rs;  // badj @ byte 64
    }
    if (blockIdx.x == 0 && threadIdx.x == 64) ws[0] = 0u;  // wsmax
    return;
  }
  int* dst = (int*)((char*)ws + 128);
  const int widx = (blockIdx.x - 10) * 256 + threadIdx.x;
  if (widx < 576) {  // w2m: dword = oc*36 + wp*4 + icg
    const int oc = widx / 36, r = widx % 36, wp = r >> 2, icg = r & 3;
    unsigned wrd = 0;
#pragma unroll
    for (int b = 0; b < 4; ++b) {
      const float v = w2[(oc * 16 + icg * 4 + b) * 9 + wp];
      wrd |= ((unsigned)(uint8_t)(int8_t)sgn_pack_byte(v)) << (8 * b);
    }
    dst[widx] = (int)wrd;
  } else if (widx < 1728) {  // w3m
    const int t = widx - 576;
    const int oc = t / 36, r = t % 36, wp = r >> 2, icg = r & 3;
    unsigned wrd = 0;
#pragma unroll
    for (int b = 0; b < 4; ++b) {
      const float v = w3[(oc * 16 + icg * 4 + b) * 9 + wp];
      wrd |= ((unsigned)(uint8_t)(int8_t)sgn_pack_byte(v)) << (8 * b);
    }
    dst[widx] = (int)wrd;
  } else if (widx < 11408) {  // sw: dword = j*968 + pos*8 + cg, byte b: c=4cg+b
    const int t = widx - 1728;
    const int j = t / 968, r = t % 968, pos = r >> 3, cg = r & 7;
    unsigned wrd = 0;
#pragma unroll
    for (int b = 0; b < 4; ++b) {
      const float v = wfc[j * 3872 + (cg * 4 + b) * 121 + pos];
      wrd |= ((unsigned)(uint8_t)(int8_t)sgn_pack_byte(v)) << (8 * b);
    }
    dst[widx] = (int)wrd;
  }
}

// Global max(|conv1|): 8 images per block => B/8 blocks.
__global__ __launch_bounds__(256) void k_conv1max(const float* __restrict__ x,
                                                  const float* __restrict__ w1,
                                                  unsigned* __restrict__ ws_max,
                                                  int B) {
  __shared__ __align__(8) float xs[784];
  __shared__ __align__(8) float w1t[144];
  __shared__ float wred[4];
  if (threadIdx.x < 144) w1t[(threadIdx.x % 9) * 16 + (threadIdx.x / 9)] = w1[threadIdx.x];

  const f2* w1t2 = (const f2*)w1t;
  float m = 0.f;
  const int im0 = blockIdx.x * 8;
  const int im1 = (im0 + 8 < B) ? im0 + 8 : B;
  for (int im = im0; im < im1; ++im) {
    __syncthreads();  // protect xs from previous iteration's readers
    const float* xi = x + (size_t)im * 784;
    for (int i = threadIdx.x; i < 784; i += 256) xs[i] = xi[i];
    __syncthreads();
    for (int px = threadIdx.x; px < 676; px += 256) {
      const int oy = px / 26, ox = px - oy * 26;
      float xw[9];
#pragma unroll
      for (int r = 0; r < 3; ++r)
#pragma unroll
        for (int cc = 0; cc < 3; ++cc) xw[r * 3 + cc] = xs[(oy + r) * 28 + ox + cc];
#pragma unroll
      for (int cw = 0; cw < 8; ++cw) {
        f2 h = {0.f, 0.f};
#pragma unroll
        for (int i = 0; i < 9; ++i) {
          const f2 s = {xw[i], xw[i]};
          h += w1t2[i * 8 + cw] * s;
        }
        m = fmaxf(m, fmaxf(fabsf(h.x), fabsf(h.y)));
      }
    }
  }
#pragma unroll
  for (int off = 32; off; off >>= 1) m = fmaxf(m, __shfl_down(m, off, 64));
  if ((threadIdx.x & 63) == 0) wred[threadIdx.x >> 6] = m;
  __syncthreads();
  if (threadIdx.x == 0) {
    const float mm = fmaxf(fmaxf(wred[0], wred[1]), fmaxf(wred[2], wred[3]));
    atomicMax(ws_max, __float_as_uint(mm));
  }
}

// ---------------------------------------------------------------------------
// k_forward LDS (31616 B):
//  [0,15488):     ph1-2: xs(3136)@0 w1t(576)@3136 a1(10816)@3712
//                 ph3-4: h3 [484 px][32 ch] 0..2-encoded
//  [15488,24704): ph2-3: h2 [576 px][16 ch] +-1
//                 ph4-5: p4 [121][48B] n-bytes @15488; out_acc[10] @21296
//  [24704,31616): w2m(2304) w3m(4608)  (loaded coalesced from d_ws)
// NOTE: plain __launch_bounds__(256) — adding a min-waves arg makes the
// allocator split the unified VGPR/AGPR file (cap 64) and spill ~50 dw/thread
// (R4: 426 MB scratch writes/dispatch). Do not re-add it.
// ---------------------------------------------------------------------------
__global__ __launch_bounds__(256) void k_forward(
    const float* __restrict__ x, const float* __restrict__ w1,
    const int* __restrict__ wpack,   // d_ws+128: w2m(576) | w3m(1152)
    const int* __restrict__ sw,      // d_ws+7040: [10][968] words
    const float* __restrict__ badj,  // d_ws+64: [10]
    const unsigned* __restrict__ ws_max, float* __restrict__ out) {
  __shared__ __align__(16) char smem[31616];
  float* xs = (float*)(smem);
  float* w1t = (float*)(smem + 3136);
  int8_t* a1b = (int8_t*)(smem + 3712);
  int* h3w = (int*)(smem);             // [484][8] dwords
  int* h2w = (int*)(smem + 15488);     // [576][4] dwords
  int* p4w = (int*)(smem + 15488);     // [121][12] dwords (48 B padded)
  int* out_acc = (int*)(smem + 21296);
  int* wlds = (int*)(smem + 24704);    // w2m(576) | w3m(1152)
  const int8_t* w2m = (const int8_t*)wlds;
  const int8_t* w3m = (const int8_t*)(wlds + 576);

  const int tid = threadIdx.x;
  const float* xi = x + (size_t)blockIdx.x * 784;
  for (int i = tid; i < 784; i += 256) xs[i] = xi[i];
  if (tid < 144) w1t[(tid % 9) * 16 + (tid / 9)] = w1[tid];
  for (int i = tid; i < 1728; i += 256) wlds[i] = wpack[i];  // coalesced
  __syncthreads();

  // Phase 1: conv1 -> ternary a1 pixel-major.
  const float scale = __uint_as_float(*ws_max) / 127.0f + 1e-8f;
  const float thr = 0.5f * scale;
  const f2* w1t2 = (const f2*)w1t;
  for (int px = tid; px < 676; px += 256) {
    const int oy = px / 26, ox = px - oy * 26;
    float xw[9];
#pragma unroll
    for (int r = 0; r < 3; ++r)
#pragma unroll
      for (int cc = 0; cc < 3; ++cc) xw[r * 3 + cc] = xs[(oy + r) * 28 + ox + cc];
    unsigned wq[4] = {0u, 0u, 0u, 0u};
#pragma unroll
    for (int cw = 0; cw < 8; ++cw) {
      f2 h = {0.f, 0.f};
#pragma unroll
      for (int i = 0; i < 9; ++i) {
        const f2 s = {xw[i], xw[i]};
        h += w1t2[i * 8 + cw] * s;
      }
      const int a0 = (h.x > thr) - (h.x < -thr);
      const int a1s = (h.y > thr) - (h.y < -thr);
      wq[cw >> 1] |= ((unsigned)(uint8_t)(int8_t)a0) << (8 * ((2 * cw) & 3));
      wq[cw >> 1] |= ((unsigned)(uint8_t)(int8_t)a1s) << (8 * ((2 * cw + 1) & 3));
    }
    *(int4*)(a1b + px * 16) = make_int4((int)wq[0], (int)wq[1], (int)wq[2], (int)wq[3]);
  }
  __syncthreads();

  // MFMA lane geometry.
  const int lane = tid & 63, wv = tid >> 6;
  const int col = lane & 15, quad = lane >> 4;
  int dAct2[3], dAct3[3];
#pragma unroll
  for (int t = 0; t < 3; ++t) {
    const int wp = t * 4 + quad;  // window pixel (k-block); wp>8 dead (A zeroed)
    dAct2[t] = ((wp / 3) * 26 + wp % 3) * 16;
    dAct3[t] = ((wp / 3) * 24 + wp % 3) * 16;
  }
  const bool kq0 = (quad == 0);  // t=2: only wp=8 is a real k-block

  // Phase 2: conv2. A=sign(w2) frags in regs; 36 n-tiles of 16 pixels.
  {
    const int8_t* wb = w2m + col * 144;  // lane's oc = col
    int4v WA[3];
    WA[0] = *(const int4v*)(wb + (quad * 16));
    WA[1] = *(const int4v*)(wb + ((4 + quad) * 16));
    WA[2] = kq0 ? *(const int4v*)(wb + 128) : (int4v){0, 0, 0, 0};
    for (int nt = wv; nt < 36; nt += 4) {
      const int p = nt * 16 + col;  // output pixel (col = n)
      const int oy = p / 24, ox = p - oy * 24;
      const int8_t* abase = a1b + (oy * 26 + ox) * 16;
      int4v acc = {0, 0, 0, 0};
      acc = mfma_i8(WA[0], *(const int4v*)(abase + dAct2[0]), acc);
      acc = mfma_i8(WA[1], *(const int4v*)(abase + dAct2[1]), acc);
      acc = mfma_i8(WA[2], *(const int4v*)(abase + dAct2[2]), acc);
      // Lane holds channels 4*quad..4*quad+3 of pixel p -> one dword.
      unsigned pk = 0;
#pragma unroll
      for (int r = 0; r < 4; ++r) {
        const int v = acc[r];
        pk |= ((unsigned)(uint8_t)(int8_t)((v > 0) - (v < 0))) << (8 * r);
      }
      h2w[p * 4 + quad] = (int)pk;  // 64 consecutive dwords: conflict-free
    }
  }
  __syncthreads();

  // Phase 3: conv3. A=sign(w3) frags (2 oc-tiles) in regs; 31 px-tiles.
  {
    int4v WA[2][3];
#pragma unroll
    for (int ot = 0; ot < 2; ++ot) {
      const int8_t* wb = w3m + (ot * 16 + col) * 144;
      WA[ot][0] = *(const int4v*)(wb + (quad * 16));
      WA[ot][1] = *(const int4v*)(wb + ((4 + quad) * 16));
      WA[ot][2] = kq0 ? *(const int4v*)(wb + 128) : (int4v){0, 0, 0, 0};
    }
    for (int pt = wv; pt < 31; pt += 4) {
      const int p = pt * 16 + col;
      const int pc = (p < 484) ? p : 483;  // clamp reads for partial tile
      const int oy = pc / 22, ox = pc - oy * 22;
      const int8_t* abase = (const int8_t*)h2w + (oy * 24 + ox) * 16;
      const int4v B0 = *(const int4v*)(abase + dAct3[0]);
      const int4v B1 = *(const int4v*)(abase + dAct3[1]);
      const int4v B2 = *(const int4v*)(abase + dAct3[2]);
#pragma unroll
      for (int ot = 0; ot < 2; ++ot) {
        int4v acc = {0, 0, 0, 0};
        acc = mfma_i8(WA[ot][0], B0, acc);
        acc = mfma_i8(WA[ot][1], B1, acc);
        acc = mfma_i8(WA[ot][2], B2, acc);
        unsigned pk = 0;  // 0..2 encoding (sign+1)
#pragma unroll
        for (int r = 0; r < 4; ++r) {
          const int v = acc[r];
          pk |= ((unsigned)((v > 0) - (v < 0) + 1)) << (8 * r);
        }
        if (p < 484) h3w[p * 8 + ot * 4 + quad] = (int)pk;
      }
    }
  }
  if (tid < 10) out_acc[tid] = 0;
  __syncthreads();

  // Phase 4: avgpool via word adds. bytes <=2 each, sums <=8: no carry.
  for (int u = tid; u < 968; u += 256) {
    const int pos = u >> 3, cg = u & 7;
    const int py = pos / 11, px = pos - py * 11;
    const int base = ((2 * py) * 22 + 2 * px) * 8 + cg;
    const int n4 = h3w[base] + h3w[base + 8] + h3w[base + 176] + h3w[base + 184];
    p4w[pos * 12 + cg] = n4;  // n = s+4 per byte, [121][48B-padded]
  }
  __syncthreads();

  // Phase 5: FC. acc = sum n*sw = true_acc4 + 4*rowsum(sw); badj corrects.
  if (tid < 250) {
    const int j = tid / 25, k = tid % 25;
    const int4* p44 = (const int4*)p4w;
    int acc = 0;
    for (int pos = k; pos < 121; pos += 25) {
      const int4 pa = p44[pos * 3];
      const int4 pb = p44[pos * 3 + 1];
      const int* swr = sw + j * 968 + pos * 8;
      const int4 wa = *(const int4*)(swr);
      const int4 wbv = *(const int4*)(swr + 4);
      acc = dot4(pa.x, wa.x, acc);
      acc = dot4(pa.y, wa.y, acc);
      acc = dot4(pa.z, wa.z, acc);
      acc = dot4(pa.w, wa.w, acc);
      acc = dot4(pb.x, wbv.x, acc);
      acc = dot4(pb.y, wbv.y, acc);
      acc = dot4(pb.z, wbv.z, acc);
      acc = dot4(pb.w, wbv.w, acc);
    }
    atomicAdd(&out_acc[j], acc);
  }
  __syncthreads();
  if (tid < 10)
    out[(size_t)blockIdx.x * 10 + tid] = 0.25f * (float)out_acc[tid] + badj[tid];
}

extern "C" void kernel_launch(void* const* d_in, const int* in_sizes, int n_in,
                              void* d_out, int out_size, void* d_ws, size_t ws_size,
                              hipStream_t stream) {
  const float* x   = (const float*)d_in[0];
  const float* w1  = (const float*)d_in[1];
  const float* w2  = (const float*)d_in[2];
  const float* w3  = (const float*)d_in[3];
  const float* wfc = (const float*)d_in[4];
  const float* bfc = (const float*)d_in[5];
  float* out = (float*)d_out;
  unsigned* wsu = (unsigned*)d_ws;
  const int* wpack = (const int*)((const char*)d_ws + 128);
  const int* sw = (const int*)((const char*)d_ws + 7040);
  const float* badj = (const float*)((const char*)d_ws + 64);
  const int B = in_sizes[0] / 784;

  hipLaunchKernelGGL(k_prep, dim3(56), dim3(256), 0, stream, w2, w3, wfc, bfc, wsu);
  hipLaunchKernelGGL(k_conv1max, dim3((B + 7) / 8), dim3(256), 0, stream, x, w1, wsu, B);
  hipLaunchKernelGGL(k_forward, dim3(B), dim3(256), 0, stream, x, w1, wpack, sw,
                     badj, wsu, out);
}

// Round 6
// 263.014 us; speedup vs baseline: 3.0597x; 1.0372x over previous
//
#include <hip/hip_runtime.h>
#include <stdint.h>

// ---------------------------------------------------------------------------
// Binarized QAT CNN forward (R6): 2 images per block, pool fused into conv3.
//   conv1 (f32 pk-fma) -> fake-quant sign => ternary a1 pixel-major [676][16] i8
//   conv2: MFMA D = sign(w2)[16x144] x a1patches  => h2 [576 px][16] i8 (+-1)
//   conv3: MFMA D = sign(w3)[32x144] x h2patches; epilogue ds_add of packed
//          (sign+1) bytes straight into pool cells p4 (bytes sum <= 8: no carry)
//   FC:    dot4 vs precomputed sign(w_fc); out = 0.25*acc + badj[j]
//          (badj = b_fc - rowsum(sign w_fc) corrects the +1 encoding bias)
//
// R6 vs R5 (occupancy 22% => ~2 blocks/CU, latency/barrier-bound):
//  - 2 images/block: 5 barriers per 2 images (was 6 per image), 2x phase ILP.
//  - h3 buffer + pool phase eliminated via LDS atomic pool accumulation.
//  - conv weights read per-lane from global (L2 broadcast, loop-invariant),
//    no LDS staging. Per-image LDS 23.9 KB; block total ~47 KB => 3 blocks/CU.
//  - prep merged into k_conv1max (2 launches total).
// NOTE: plain __launch_bounds__(256) — a min-waves arg caps arch VGPRs and
// spills ~50 dw/thread (R4: 426 MB scratch writes). Do not re-add it.
//
// MFMA i8 16x16x64 lane mapping (gfx950): A: lane l holds A[m=l&15][k=16q+j];
// B: B[k=16q+j][n=l&15]; D reg r: row=(l>>4)*4+r, col=l&15. A=weights =>
// row=oc, col=pixel; lane's 4 D values = 4 consecutive channels of one pixel.
// K=144 padded to 192 by zeroing the WEIGHT fragment for k-blocks 9..11.
//
// d_ws layout: [0] u32 wsmax | [64] float badj[10] | [128] w2m 576 dw |
//              [2432] w3m 1152 dw | [7040] sw 9680 dw  (total 45760 B)
// ---------------------------------------------------------------------------

typedef int int4v __attribute__((ext_vector_type(4)));
typedef float f2 __attribute__((ext_vector_type(2)));

__device__ __forceinline__ int4v mfma_i8(int4v a, int4v b, int4v c) {
  return __builtin_amdgcn_mfma_i32_16x16x64_i8(a, b, c, 0, 0, 0);
}

__device__ __forceinline__ int dot4(int a, int b, int c) {
#if __has_builtin(__builtin_amdgcn_sdot4)
  return __builtin_amdgcn_sdot4(a, b, c, false);
#else
  int r = c;
  r += (int)(int8_t)(a)       * (int)(int8_t)(b);
  r += (int)(int8_t)(a >> 8)  * (int)(int8_t)(b >> 8);
  r += (int)(int8_t)(a >> 16) * (int)(int8_t)(b >> 16);
  r += (int)(int8_t)(a >> 24) * (int)(int8_t)(b >> 24);
  return r;
#endif
}

__device__ __forceinline__ int sgn_pack_byte(float v) {
  return (v > 0.f) - (v < 0.f);
}

// Merged prep + conv1-max. Blocks 0..9: badj rowsums (block0 zeroes wsmax).
// Blocks 10..55: weight packing. Blocks >=56: global max(|conv1|), 8 img each.
__global__ __launch_bounds__(256) void k_prep_max(
    const float* __restrict__ x, const float* __restrict__ w1,
    const float* __restrict__ w2, const float* __restrict__ w3,
    const float* __restrict__ wfc, const float* __restrict__ bfc,
    unsigned* __restrict__ ws, int B) {
  if (blockIdx.x < 10) {
    __shared__ int part[4];
    const int j = blockIdx.x;
    int s = 0;
    for (int i = threadIdx.x; i < 3872; i += 256) {
      const float v = wfc[j * 3872 + i];
      s += (v > 0.f) - (v < 0.f);
    }
#pragma unroll
    for (int off = 32; off; off >>= 1) s += __shfl_down(s, off, 64);
    if ((threadIdx.x & 63) == 0) part[threadIdx.x >> 6] = s;
    __syncthreads();
    if (threadIdx.x == 0) {
      const int rs = part[0] + part[1] + part[2] + part[3];
      ((float*)ws)[16 + j] = bfc[j] - (float)rs;  // badj @ byte 64
    }
    if (blockIdx.x == 0 && threadIdx.x == 64) ws[0] = 0u;  // wsmax
    return;
  }
  if (blockIdx.x < 56) {
    int* dst = (int*)((char*)ws + 128);
    const int widx = (blockIdx.x - 10) * 256 + threadIdx.x;
    if (widx < 576) {  // w2m: dword = oc*36 + wp*4 + icg
      const int oc = widx / 36, r = widx % 36, wp = r >> 2, icg = r & 3;
      unsigned wrd = 0;
#pragma unroll
      for (int b = 0; b < 4; ++b) {
        const float v = w2[(oc * 16 + icg * 4 + b) * 9 + wp];
        wrd |= ((unsigned)(uint8_t)(int8_t)sgn_pack_byte(v)) << (8 * b);
      }
      dst[widx] = (int)wrd;
    } else if (widx < 1728) {  // w3m
      const int t = widx - 576;
      const int oc = t / 36, r = t % 36, wp = r >> 2, icg = r & 3;
      unsigned wrd = 0;
#pragma unroll
      for (int b = 0; b < 4; ++b) {
        const float v = w3[(oc * 16 + icg * 4 + b) * 9 + wp];
        wrd |= ((unsigned)(uint8_t)(int8_t)sgn_pack_byte(v)) << (8 * b);
      }
      dst[widx] = (int)wrd;
    } else if (widx < 11408) {  // sw: dword = j*968 + pos*8 + cg
      const int t = widx - 1728;
      const int j = t / 968, r = t % 968, pos = r >> 3, cg = r & 7;
      unsigned wrd = 0;
#pragma unroll
      for (int b = 0; b < 4; ++b) {
        const float v = wfc[j * 3872 + (cg * 4 + b) * 121 + pos];
        wrd |= ((unsigned)(uint8_t)(int8_t)sgn_pack_byte(v)) << (8 * b);
      }
      dst[widx] = (int)wrd;
    }
    return;
  }
  // conv1-max over 8 images.
  __shared__ __align__(8) float xs[784];
  __shared__ __align__(8) float w1t[144];
  __shared__ float wred[4];
  if (threadIdx.x < 144) w1t[(threadIdx.x % 9) * 16 + (threadIdx.x / 9)] = w1[threadIdx.x];
  const f2* w1t2 = (const f2*)w1t;
  float m = 0.f;
  const int im0 = (blockIdx.x - 56) * 8;
  const int im1 = (im0 + 8 < B) ? im0 + 8 : B;
  for (int im = im0; im < im1; ++im) {
    __syncthreads();
    const float* xi = x + (size_t)im * 784;
    for (int i = threadIdx.x; i < 784; i += 256) xs[i] = xi[i];
    __syncthreads();
    for (int px = threadIdx.x; px < 676; px += 256) {
      const int oy = px / 26, ox = px - oy * 26;
      float xw[9];
#pragma unroll
      for (int r = 0; r < 3; ++r)
#pragma unroll
        for (int cc = 0; cc < 3; ++cc) xw[r * 3 + cc] = xs[(oy + r) * 28 + ox + cc];
#pragma unroll
      for (int cw = 0; cw < 8; ++cw) {
        f2 h = {0.f, 0.f};
#pragma unroll
        for (int i = 0; i < 9; ++i) {
          const f2 s = {xw[i], xw[i]};
          h += w1t2[i * 8 + cw] * s;
        }
        m = fmaxf(m, fmaxf(fabsf(h.x), fabsf(h.y)));
      }
    }
  }
#pragma unroll
  for (int off = 32; off; off >>= 1) m = fmaxf(m, __shfl_down(m, off, 64));
  if ((threadIdx.x & 63) == 0) wred[threadIdx.x >> 6] = m;
  __syncthreads();
  if (threadIdx.x == 0) {
    const float mm = fmaxf(fmaxf(wred[0], wred[1]), fmaxf(wred[2], wred[3]));
    atomicMax(ws, __float_as_uint(mm));
  }
}

// ---------------------------------------------------------------------------
// k_forward: 2 images per block. LDS 47952 B => 3 blocks/CU (LDS cap).
// Per-image region (stride 23936): a1 @0 (10816) | h2 @10816 (9216) |
//   p4 @20032 (3872, [121][8 dw], bytes = pooled (sign+1) sums).
// xs[img] aliases h2[img] (+10816); w1t aliases h2[0]+3136. out_acc @47872.
// ---------------------------------------------------------------------------
__global__ __launch_bounds__(256) void k_forward(
    const float* __restrict__ x, const float* __restrict__ w1,
    const int* __restrict__ wpack,   // d_ws+128: w2m(576 dw) | w3m(1152 dw)
    const int* __restrict__ sw,      // d_ws+7040: [10][968] dw
    const float* __restrict__ badj,  // d_ws+64: [10]
    const unsigned* __restrict__ ws_max, float* __restrict__ out, int B) {
  __shared__ __align__(16) char smem[47952];
  constexpr int RIMG = 23936;
  int* out_acc = (int*)(smem + 47872);  // [2][10]

  const int tid = threadIdx.x;
  const int img0 = blockIdx.x * 2;
  const bool has1 = (img0 + 1) < B;

  // Stage: x -> xs[img] (aliasing h2 regions), w1t, zero p4 + out_acc.
  for (int u = tid; u < 1568; u += 256) {
    const int img = (u >= 784), i = img ? u - 784 : u;
    const float v = x[(size_t)(img0 + (img & (int)has1)) * 784 + i];
    *(float*)(smem + img * RIMG + 10816 + i * 4) = v;
  }
  if (tid < 144) *(float*)(smem + 10816 + 3136 + ((tid % 9) * 16 + tid / 9) * 4) = w1[tid];
  for (int u = tid; u < 1936; u += 256) {
    const int img = (u >= 968), i = img ? u - 968 : u;
    *(int*)(smem + img * RIMG + 20032 + i * 4) = 0;
  }
  if (tid < 20) out_acc[tid] = 0;
  __syncthreads();

  // Phase 1: conv1 -> ternary a1 pixel-major, both images.
  const float scale = __uint_as_float(*ws_max) / 127.0f + 1e-8f;
  const float thr = 0.5f * scale;
  const f2* w1t2 = (const f2*)(smem + 10816 + 3136);
  for (int u = tid; u < 1352; u += 256) {
    const int img = (u >= 676), px = img ? u - 676 : u;
    const float* xs = (const float*)(smem + img * RIMG + 10816);
    const int oy = px / 26, ox = px - oy * 26;
    float xw[9];
#pragma unroll
    for (int r = 0; r < 3; ++r)
#pragma unroll
      for (int cc = 0; cc < 3; ++cc) xw[r * 3 + cc] = xs[(oy + r) * 28 + ox + cc];
    unsigned wq[4] = {0u, 0u, 0u, 0u};
#pragma unroll
    for (int cw = 0; cw < 8; ++cw) {
      f2 h = {0.f, 0.f};
#pragma unroll
      for (int i = 0; i < 9; ++i) {
        const f2 s = {xw[i], xw[i]};
        h += w1t2[i * 8 + cw] * s;
      }
      const int a0 = (h.x > thr) - (h.x < -thr);
      const int a1s = (h.y > thr) - (h.y < -thr);
      wq[cw >> 1] |= ((unsigned)(uint8_t)(int8_t)a0) << (8 * ((2 * cw) & 3));
      wq[cw >> 1] |= ((unsigned)(uint8_t)(int8_t)a1s) << (8 * ((2 * cw + 1) & 3));
    }
    *(int4*)(smem + img * RIMG + px * 16) =
        make_int4((int)wq[0], (int)wq[1], (int)wq[2], (int)wq[3]);
  }
  __syncthreads();

  // MFMA lane geometry.
  const int lane = tid & 63, wv = tid >> 6;
  const int col = lane & 15, quad = lane >> 4;
  int dAct2[3], dAct3[3];
#pragma unroll
  for (int t = 0; t < 3; ++t) {
    const int wp = t * 4 + quad;  // window pixel (k-block); wp>8 dead (A zeroed)
    dAct2[t] = ((wp / 3) * 26 + wp % 3) * 16;
    dAct3[t] = ((wp / 3) * 24 + wp % 3) * 16;
  }
  const bool kq0 = (quad == 0);  // t=2: only wp=8 is a real k-block

  // Phase 2: conv2. A=sign(w2) frags from global (L2 broadcast, invariant).
  {
    const int* wb = wpack + col * 36;  // lane's oc = col
    int4v WA[3];
    WA[0] = *(const int4v*)(wb + quad * 4);
    WA[1] = *(const int4v*)(wb + 16 + quad * 4);
    WA[2] = kq0 ? *(const int4v*)(wb + 32) : (int4v){0, 0, 0, 0};
#pragma unroll
    for (int img = 0; img < 2; ++img) {
      const int8_t* a1b = (const int8_t*)(smem + img * RIMG);
      int8_t* h2b = (int8_t*)(smem + img * RIMG + 10816);
      for (int nt = wv; nt < 36; nt += 4) {
        const int p = nt * 16 + col;  // output pixel (col = n)
        const int oy = p / 24, ox = p - oy * 24;
        const int8_t* abase = a1b + (oy * 26 + ox) * 16;
        int4v acc = {0, 0, 0, 0};
        acc = mfma_i8(WA[0], *(const int4v*)(abase + dAct2[0]), acc);
        acc = mfma_i8(WA[1], *(const int4v*)(abase + dAct2[1]), acc);
        acc = mfma_i8(WA[2], *(const int4v*)(abase + dAct2[2]), acc);
        unsigned pk = 0;  // channels 4*quad..+3 of pixel p -> one dword
#pragma unroll
        for (int r = 0; r < 4; ++r) {
          const int v = acc[r];
          pk |= ((unsigned)(uint8_t)(int8_t)((v > 0) - (v < 0))) << (8 * r);
        }
        *(int*)(h2b + p * 16 + quad * 4) = (int)pk;  // conflict-free
      }
    }
  }
  __syncthreads();

  // Phase 3: conv3 + fused pool. A=sign(w3) frags (2 oc-tiles) from global.
  {
    int4v WA[2][3];
#pragma unroll
    for (int ot = 0; ot < 2; ++ot) {
      const int* wb = wpack + 576 + (ot * 16 + col) * 36;
      WA[ot][0] = *(const int4v*)(wb + quad * 4);
      WA[ot][1] = *(const int4v*)(wb + 16 + quad * 4);
      WA[ot][2] = kq0 ? *(const int4v*)(wb + 32) : (int4v){0, 0, 0, 0};
    }
#pragma unroll
    for (int img = 0; img < 2; ++img) {
      const int8_t* h2b = (const int8_t*)(smem + img * RIMG + 10816);
      int* p4 = (int*)(smem + img * RIMG + 20032);
      for (int pt = wv; pt < 31; pt += 4) {
        const int p = pt * 16 + col;
        const int pc = (p < 484) ? p : 483;  // clamp reads for partial tile
        const int oy = pc / 22, ox = pc - oy * 22;
        const int8_t* abase = h2b + (oy * 24 + ox) * 16;
        const int4v B0 = *(const int4v*)(abase + dAct3[0]);
        const int4v B1 = *(const int4v*)(abase + dAct3[1]);
        const int4v B2 = *(const int4v*)(abase + dAct3[2]);
        const int pos = (oy >> 1) * 11 + (ox >> 1);  // pool cell
#pragma unroll
        for (int ot = 0; ot < 2; ++ot) {
          int4v acc = {0, 0, 0, 0};
          acc = mfma_i8(WA[ot][0], B0, acc);
          acc = mfma_i8(WA[ot][1], B1, acc);
          acc = mfma_i8(WA[ot][2], B2, acc);
          unsigned pk = 0;  // (sign+1) per byte, 0..2
#pragma unroll
          for (int r = 0; r < 4; ++r) {
            const int v = acc[r];
            pk |= ((unsigned)((v > 0) - (v < 0) + 1)) << (8 * r);
          }
          if (p < 484) atomicAdd(&p4[pos * 8 + ot * 4 + quad], (int)pk);
        }
      }
    }
  }
  __syncthreads();

  // Phase 4: FC. acc = sum n*sw = true_acc4 + 4*rowsum(sw); badj corrects.
  for (int u = tid; u < 500; u += 256) {
    const int img = u / 250, r = u - img * 250;
    const int j = r / 25, k = r - j * 25;
    const int4* p44 = (const int4*)(smem + img * RIMG + 20032);
    int acc = 0;
    for (int pos = k; pos < 121; pos += 25) {
      const int4 pa = p44[pos * 2];
      const int4 pb = p44[pos * 2 + 1];
      const int* swr = sw + j * 968 + pos * 8;
      const int4 wa = *(const int4*)(swr);
      const int4 wbv = *(const int4*)(swr + 4);
      acc = dot4(pa.x, wa.x, acc);
      acc = dot4(pa.y, wa.y, acc);
      acc = dot4(pa.z, wa.z, acc);
      acc = dot4(pa.w, wa.w, acc);
      acc = dot4(pb.x, wbv.x, acc);
      acc = dot4(pb.y, wbv.y, acc);
      acc = dot4(pb.z, wbv.z, acc);
      acc = dot4(pb.w, wbv.w, acc);
    }
    atomicAdd(&out_acc[img * 10 + j], acc);
  }
  __syncthreads();
  if (tid < 20) {
    const int img = tid / 10, j = tid - img * 10;
    if (img == 0 || has1)
      out[(size_t)(img0 + img) * 10 + j] = 0.25f * (float)out_acc[tid] + badj[j];
  }
}

extern "C" void kernel_launch(void* const* d_in, const int* in_sizes, int n_in,
                              void* d_out, int out_size, void* d_ws, size_t ws_size,
                              hipStream_t stream) {
  const float* x   = (const float*)d_in[0];
  const float* w1  = (const float*)d_in[1];
  const float* w2  = (const float*)d_in[2];
  const float* w3  = (const float*)d_in[3];
  const float* wfc = (const float*)d_in[4];
  const float* bfc = (const float*)d_in[5];
  float* out = (float*)d_out;
  unsigned* wsu = (unsigned*)d_ws;
  const int* wpack = (const int*)((const char*)d_ws + 128);
  const int* sw = (const int*)((const char*)d_ws + 7040);
  const float* badj = (const float*)((const char*)d_ws + 64);
  const int B = in_sizes[0] / 784;

  hipLaunchKernelGGL(k_prep_max, dim3(56 + (B + 7) / 8), dim3(256), 0, stream,
                     x, w1, w2, w3, wfc, bfc, wsu, B);
  hipLaunchKernelGGL(k_forward, dim3((B + 1) / 2), dim3(256), 0, stream, x, w1,
                     wpack, sw, badj, wsu, out, B);
}